// Round 5
// baseline (947.883 us; speedup 1.0000x reference)
//
#include <hip/hip_runtime.h>

typedef unsigned int uint;
typedef unsigned short ushort;
typedef unsigned long long u64;

typedef __attribute__((ext_vector_type(8))) short short8;
typedef __attribute__((ext_vector_type(4))) float floatx4;

// ---------------- helpers ----------------
__device__ inline ushort bf16rne(float v) {
  uint b = __float_as_uint(v);
  uint r = (b + 0x7fffu + ((b >> 16) & 1u)) >> 16;
  return (ushort)r;
}

__device__ inline void gl_lds16(const void* g, void* l) {
  __builtin_amdgcn_global_load_lds(
      (const __attribute__((address_space(1))) unsigned int*)g,
      (__attribute__((address_space(3))) unsigned int*)l, 16, 0, 0);
}

// ---------------- prep: x -> padded transposed bf16 hi/lo [66][66][1024] ----
__global__ __launch_bounds__(256) void prep_x(const float* __restrict__ x,
                                              ushort* __restrict__ xh,
                                              ushort* __restrict__ xl) {
  __shared__ float tile[64 * 65];
  int ci0 = blockIdx.x * 64, y = blockIdx.y, t = threadIdx.x;
#pragma unroll
  for (int it = 0; it < 16; ++it) {
    int L = t + 256 * it;
    int cl = L >> 6, xx = L & 63;
    tile[cl * 65 + xx] = x[(size_t)(ci0 + cl) * 4096 + y * 64 + xx];
  }
  __syncthreads();
#pragma unroll
  for (int it = 0; it < 16; ++it) {
    int L = t + 256 * it;
    int xx = L >> 6, cl = L & 63;
    float v = tile[cl * 65 + xx];
    ushort h2 = bf16rne(v);
    float hf = __uint_as_float((uint)h2 << 16);
    ushort l2 = bf16rne(v - hf);
    size_t oi = ((size_t)((y + 1) * 66 + (xx + 1))) * 1024 + ci0 + cl;
    xh[oi] = h2;
    xl[oi] = l2;
  }
}

// ---------------- prep: conv_w[co][ci][3][3] -> wT[off][co][ci] hi/lo -------
__global__ __launch_bounds__(256) void prep_w(const float* __restrict__ w,
                                              ushort* __restrict__ wh,
                                              ushort* __restrict__ wl) {
  __shared__ float tile[2304];  // 256 ci x 9 off
  int co = blockIdx.x, ci0 = blockIdx.y * 256, t = threadIdx.x;
  const float* src = w + ((size_t)co * 1024 + ci0) * 9;
  for (int i = t; i < 2304; i += 256) tile[i] = src[i];
  __syncthreads();
  int ci = ci0 + t;
#pragma unroll
  for (int off = 0; off < 9; ++off) {
    float v = tile[t * 9 + off];
    ushort h2 = bf16rne(v);
    float hf = __uint_as_float((uint)h2 << 16);
    ushort l2 = bf16rne(v - hf);
    size_t oi = ((size_t)off << 20) | ((size_t)co << 10) | (size_t)ci;
    wh[oi] = h2;
    wl[oi] = l2;
  }
}

// ---------------- prep: head weights [128][1024] hi/lo + bias[128] ----------
__global__ __launch_bounds__(256) void prep_head(
    const float* __restrict__ score_w, const float* __restrict__ loc_w,
    const float* __restrict__ score_b, const float* __restrict__ loc_b,
    ushort* __restrict__ wh, ushort* __restrict__ wl, float* __restrict__ bh) {
  int idx = blockIdx.x * 256 + threadIdx.x;  // < 131072
  int o = idx >> 10, ci = idx & 1023;
  float v = 0.f;
  if (o < 15) v = score_w[o * 1024 + ci];
  else if (o < 75) v = loc_w[(o - 15) * 1024 + ci];
  ushort h2 = bf16rne(v);
  float hf = __uint_as_float((uint)h2 << 16);
  wh[idx] = h2;
  wl[idx] = bf16rne(v - hf);
  if (idx < 128) bh[idx] = (idx < 15) ? score_b[idx] : ((idx < 75) ? loc_b[idx - 15] : 0.f);
}

// ---------------- bf16x3 GEMM: C[m][n] = sum_k A[m][k]*B[n][k] --------------
// Tile 128 x BN, 256 threads (4 waves as 2x2). K-accumulation order is
// BIT-IDENTICAL to the verified round-0 kernel: one block owns a full output
// tile and walks chunks 0..nChunks-1 sequentially, MFMA order hh,hl,lh per
// chunk. (Split-K reordering flips a knife-edge NMS decision downstream --
// three rounds of identical absmax=720 failures -- so sum order is frozen.)
// BN=64 for the conv: grid (32,16)=512 blocks -> 2 blocks/CU (48KB LDS each),
// so one block's barrier/stage drains hide under the other's MFMAs.
// LDS layout per section: SEG-MAJOR [4 k-octets][rows][16B]. A fragment
// ds_read_b128 (16 lanes, same k-octet, consecutive rows) covers 256
// CONTIGUOUS bytes = all 32 banks x2 -> no intra-group bank conflicts
// (row-major was an 8-way conflict at 64B stride = the 18.9M counter).
// Staging keeps the proven linear-dest global_load_lds; only the slot
// decode changes (row = L % rows, seg = L / rows).
// IM2COL=1: A from xpadT (im2col, K=9216), epilogue bias+relu -> h hi/lo bf16
// IM2COL=0: A = h[m][k] (K=1024), epilogue bias -> raw f32 [m][128]
template <int IM2COL, int BN>
__global__ __launch_bounds__(256, 1) void gemm_bf16x3(
    const ushort* __restrict__ Ahi, const ushort* __restrict__ Alo,
    const ushort* __restrict__ Bhi, const ushort* __restrict__ Blo,
    const float* __restrict__ bias, int nChunks, float* __restrict__ outRaw,
    ushort* __restrict__ outHi, ushort* __restrict__ outLo) {
  constexpr int ASEC = 128 * 32;       // ushorts per A section
  constexpr int BSEC = BN * 32;        // ushorts per B section
  constexpr int BUFU = 2 * ASEC + 2 * BSEC;  // ushorts per buffer
  constexpr int NJ = BN / 32;          // n-fragments per wave
  __shared__ ushort sm[2 * BUFU];      // BN=128: 64KB, BN=64: 48KB
  const int t = threadIdx.x;
  const int m0 = blockIdx.x * 128;
  const int n0 = blockIdx.y * BN;

  auto stage = [&](int c, int bufIdx) {
    ushort* secAh = sm + bufIdx * BUFU;
    ushort* secAl = secAh + ASEC;
    ushort* secBh = secAl + ASEC;
    ushort* secBl = secBh + BSEC;
    int off = 0, cc = 0, oy = 0, ox = 0;
    if (IM2COL) {
      off = c >> 5;        // 0..8  (ky*3+kx)
      cc = (c & 31) << 5;  // ci0
      oy = off / 3;
      ox = off - 3 * oy;
    }
    // A sections: 512 slots of 16B, seg-major (row = L&127, seg = L>>7)
#pragma unroll
    for (int q = 0; q < 2; ++q) {
      int L = t + 256 * q;
      int row = L & 127, seg = L >> 7;
      size_t aoff;
      if (IM2COL) {
        int m = m0 + row, y = m >> 6, xq = m & 63;
        aoff = ((size_t)((y + oy) * 66 + (xq + ox)) * 1024 + (size_t)cc) * 2 + seg * 16;
      } else {
        aoff = (((size_t)(m0 + row) << 10) + (size_t)c * 32) * 2 + seg * 16;
      }
      gl_lds16((const char*)Ahi + aoff, (char*)secAh + L * 16);
      gl_lds16((const char*)Alo + aoff, (char*)secAl + L * 16);
    }
    // B sections: BN*4 slots of 16B, seg-major (row = L%BN, seg = L/BN)
#pragma unroll
    for (int q = 0; q < BN / 64; ++q) {
      int L = t + 256 * q;
      int row = L & (BN - 1), seg = L / BN;
      size_t boff;
      if (IM2COL) {
        boff = (((size_t)off << 20) + ((size_t)(n0 + row) << 10) + (size_t)cc) * 2 + seg * 16;
      } else {
        boff = (((size_t)(n0 + row) << 10) + (size_t)c * 32) * 2 + seg * 16;
      }
      gl_lds16((const char*)Bhi + boff, (char*)secBh + L * 16);
      gl_lds16((const char*)Blo + boff, (char*)secBl + L * 16);
    }
  };

  const int lane = t & 63, wv = t >> 6;
  const int wm = (wv & 1) * 64, wn = (wv >> 1) * (BN / 2);
  const int rA = wm + (lane & 15);
  const int rB = wn + (lane & 15);
  const int segA = (lane >> 4) * 2048;      // A seg region base (bytes)
  const int segB = (lane >> 4) * (BN * 16); // B seg region base (bytes)

  floatx4 acc[4][NJ];
#pragma unroll
  for (int i = 0; i < 4; ++i)
#pragma unroll
    for (int j = 0; j < NJ; ++j) acc[i][j] = (floatx4){0.f, 0.f, 0.f, 0.f};

  stage(0, 0);
  for (int kc = 0; kc < nChunks; ++kc) {
    __syncthreads();  // staged chunk kc landed; prev compute done
    if (kc + 1 < nChunks) stage(kc + 1, (kc + 1) & 1);  // overlap with compute
    const ushort* sb = sm + (kc & 1) * BUFU;
    const char* cAh = (const char*)sb;
    const char* cAl = (const char*)(sb + ASEC);
    const char* cBh = (const char*)(sb + 2 * ASEC);
    const char* cBl = (const char*)(sb + 2 * ASEC + BSEC);
    short8 ah[4], al[4], bh2[NJ], bl2[NJ];
#pragma unroll
    for (int i = 0; i < 4; ++i) {
      int pa = segA + (rA + 16 * i) * 16;
      ah[i] = *(const short8*)(cAh + pa);
      al[i] = *(const short8*)(cAl + pa);
    }
#pragma unroll
    for (int j = 0; j < NJ; ++j) {
      int pb = segB + (rB + 16 * j) * 16;
      bh2[j] = *(const short8*)(cBh + pb);
      bl2[j] = *(const short8*)(cBl + pb);
    }
#pragma unroll
    for (int i = 0; i < 4; ++i)
#pragma unroll
      for (int j = 0; j < NJ; ++j) {
        acc[i][j] = __builtin_amdgcn_mfma_f32_16x16x32_bf16(ah[i], bh2[j], acc[i][j], 0, 0, 0);
        acc[i][j] = __builtin_amdgcn_mfma_f32_16x16x32_bf16(ah[i], bl2[j], acc[i][j], 0, 0, 0);
        acc[i][j] = __builtin_amdgcn_mfma_f32_16x16x32_bf16(al[i], bh2[j], acc[i][j], 0, 0, 0);
      }
  }

#pragma unroll
  for (int i = 0; i < 4; ++i)
#pragma unroll
    for (int j = 0; j < NJ; ++j) {
      int nn = n0 + wn + 16 * j + (lane & 15);
      float bv = bias[nn];
#pragma unroll
      for (int r = 0; r < 4; ++r) {
        int mm = m0 + wm + 16 * i + (lane >> 4) * 4 + r;  // C: row=(lane>>4)*4+reg
        float v = acc[i][j][r] + bv;
        if (IM2COL) {
          v = fmaxf(v, 0.f);
          ushort h2 = bf16rne(v);
          float hf = __uint_as_float((uint)h2 << 16);
          ushort l2 = bf16rne(v - hf);
          outHi[(size_t)mm * 1024 + nn] = h2;
          outLo[(size_t)mm * 1024 + nn] = l2;
        } else {
          outRaw[(size_t)mm * 128 + nn] = v;
        }
      }
    }
}

// ---------------- decode + key + histogram ----------------------------------
__global__ __launch_bounds__(256) void decode_k(const float* __restrict__ raw,
                                                float* __restrict__ scores,
                                                float4* __restrict__ boxes,
                                                uint* __restrict__ key32,
                                                uint* __restrict__ hist) {
  int i = blockIdx.x * 256 + threadIdx.x;  // exactly 61440
  int m = i / 15, a = i - m * 15;
  int y = m >> 6, x = m & 63;
  const float* rp = raw + (size_t)m * 128;
  float logit = rp[a];
  float dx = rp[15 + 4 * a], dy = rp[16 + 4 * a];
  float dw = rp[17 + 4 * a], dh = rp[18 + 4 * a];
  int rr = a / 5, ss = a - rr * 5;
  float sc5 = (float)(2 << ss);
  float W = ((rr == 0) ? 23.f : (rr == 1) ? 16.f : 11.f) * sc5;
  float H = ((rr == 0) ? 12.f : (rr == 1) ? 16.f : 22.f) * sc5;
  float aw = W - 1.f, ah = H - 1.f;
  float ax = x * 16.f + 7.5f, ay = y * 16.f + 7.5f;
  float ox = dx * aw + ax, oyc = dy * ah + ay;
  float ow = expf(fminf(dw, 4.14f)) * aw * 0.5f;
  float oh = expf(fminf(dh, 4.14f)) * ah * 0.5f;
  float x1 = fminf(fmaxf(ox - ow, 0.f), 1023.f);
  float y1 = fminf(fmaxf(oyc - oh, 0.f), 1023.f);
  float x2 = fminf(fmaxf(ox + ow, 0.f), 1023.f);
  float y2 = fminf(fmaxf(oyc + oh, 0.f), 1023.f);
  bool inval = ((x2 - x1) < 16.f) || ((y2 - y1) < 16.f);
  float sc = inval ? -1.f : (1.f / (1.f + expf(-logit)));
  scores[i] = sc;
  boxes[i] = inval ? make_float4(-1.f, -1.f, -1.f, -1.f) : make_float4(x1, y1, x2, y2);
  uint kb = __float_as_uint(sc);
  uint key = (kb & 0x80000000u) ? ~kb : (kb | 0x80000000u);
  key32[i] = key;
  atomicAdd(&hist[key >> 16], 1u);
}

// ---------------- find 16-bit prefix threshold for top-6000 -----------------
__global__ __launch_bounds__(256) void find_t16(const uint* __restrict__ hist,
                                                uint* __restrict__ selT) {
  __shared__ uint ps[256];
  __shared__ int segS;
  int t = threadIdx.x;
  uint s = 0;
  const uint* hp = hist + t * 256;
  for (int i = 0; i < 256; ++i) s += hp[i];
  ps[t] = s;
  __syncthreads();
  for (int d = 1; d < 256; d <<= 1) {
    uint v = ps[t] + ((t + d < 256) ? ps[t + d] : 0u);
    __syncthreads();
    ps[t] = v;
    __syncthreads();
  }
  if (ps[t] >= 6000u && (t == 255 || ps[t + 1] < 6000u)) segS = t;
  __syncthreads();
  int sg = segS;
  uint base = (sg == 255) ? 0u : ps[sg + 1];
  uint h2 = hist[sg * 256 + t];
  __syncthreads();
  ps[t] = h2;
  __syncthreads();
  for (int d = 1; d < 256; d <<= 1) {
    uint v = ps[t] + ((t + d < 256) ? ps[t + d] : 0u);
    __syncthreads();
    ps[t] = v;
    __syncthreads();
  }
  if (base + ps[t] >= 6000u && (t == 255 || base + ps[t + 1] < 6000u))
    *selT = (uint)(sg * 256 + t);
}

// ---------------- gather candidates (prefix >= T16) -------------------------
__global__ __launch_bounds__(256) void gather_k(const uint* __restrict__ key32,
                                                const uint* __restrict__ selT,
                                                uint* __restrict__ cnt,
                                                u64* __restrict__ cand) {
  int i = blockIdx.x * 256 + threadIdx.x;  // exactly 61440
  uint T = *selT;
  uint k = key32[i];
  if ((k >> 16) >= T) {
    uint pos = atomicAdd(cnt, 1u);
    if (pos < 8192) cand[pos] = ((u64)k << 32) | (u64)(~(uint)i);
  }
}

// ---------------- single-block bitonic sort (desc) + gather top-6000 --------
__global__ __launch_bounds__(1024) void sort_gather(
    const u64* __restrict__ cand, const uint* __restrict__ cnt,
    const float* __restrict__ scores, const float4* __restrict__ boxes,
    float* __restrict__ sortedS, float4* __restrict__ sortedB) {
  extern __shared__ u64 sk[];  // 8192 * 8 = 64 KB
  int t = threadIdx.x;
  int C = (int)*cnt;
  if (C > 8192) C = 8192;
  for (int j = t; j < 8192; j += 1024) sk[j] = (j < C) ? cand[j] : 0ull;
  __syncthreads();
  for (int k = 2; k <= 8192; k <<= 1) {
    for (int j2 = k >> 1; j2 > 0; j2 >>= 1) {
      for (int p = t; p < 4096; p += 1024) {
        int i = ((p & ~(j2 - 1)) << 1) | (p & (j2 - 1));
        int ix = i | j2;
        u64 a = sk[i], b = sk[ix];
        bool ddir = (i & k) != 0;
        if ((a < b) != ddir) { sk[i] = b; sk[ix] = a; }
      }
      __syncthreads();
    }
  }
  for (int j = t; j < 6016; j += 1024) {
    if (j < 6000) {
      u64 key = sk[j];
      uint idx = ~(uint)(key & 0xffffffffu);
      sortedS[j] = scores[idx];
      sortedB[j] = boxes[idx];
    } else {
      sortedS[j] = -1.f;
      sortedB[j] = make_float4(0.f, 0.f, 0.f, 0.f);
    }
  }
}

// ---------------- IoU suppression bitmask: mask[row][128 u64 words] ---------
__global__ __launch_bounds__(64) void iou_mask(const float4* __restrict__ boxes,
                                               u64* __restrict__ mask) {
  __shared__ float cx1[64], cy1[64], cx2[64], cy2[64], car[64];
  int bi = blockIdx.x, bj = blockIdx.y, t = threadIdx.x;
  float4 cb = boxes[bj * 64 + t];
  cx1[t] = cb.x; cy1[t] = cb.y; cx2[t] = cb.z; cy2[t] = cb.w;
  car[t] = (cb.z - cb.x) * (cb.w - cb.y);
  __syncthreads();
  int r = bi * 64 + t;
  float4 rb = boxes[r];
  float ra = (rb.z - rb.x) * (rb.w - rb.y);
  u64 wd = 0;
#pragma unroll 8
  for (int j = 0; j < 64; ++j) {
    float iw = fmaxf(fminf(rb.z, cx2[j]) - fmaxf(rb.x, cx1[j]), 0.f);
    float ih = fmaxf(fminf(rb.w, cy2[j]) - fmaxf(rb.y, cy1[j]), 0.f);
    float inter = iw * ih;
    float iou = inter / (ra + car[j] - inter + 1e-12f);
    if (iou > 0.7f && r != bj * 64 + j) wd |= (1ull << j);
  }
  mask[(size_t)r * 128 + bj] = wd;
}

// ---------------- serial NMS scan (1 wave), word-skipping, early stop -------
__global__ __launch_bounds__(64) void nms_scan(const u64* __restrict__ mask,
                                               const float* __restrict__ sortedS,
                                               const float4* __restrict__ sortedB,
                                               float* __restrict__ out) {
  __shared__ int klist[300];
  int lane = threadIdx.x;
  u64 Sx = 0, Sy = 0;  // lane l owns suppression words 2l and 2l+1
  for (int w2 = 0; w2 < 94; ++w2) {
    bool neg = sortedS[w2 * 64 + lane] < 0.f;
    u64 m2 = __ballot(neg);
    if ((w2 >> 1) == lane) { if (w2 & 1) Sy = m2; else Sx = m2; }
  }
  int count = 0;
  for (int w2 = 0; w2 < 94; ++w2) {
    u64 cur = __shfl((w2 & 1) ? Sy : Sx, w2 >> 1);
    u64 rem = ~cur;
    if (w2 == 93) rem &= (1ull << 48) - 1;  // rows 6000..6015 are pad
    while (rem) {
      int b = __builtin_ctzll(rem);
      int i = w2 * 64 + b;
      if (lane == 0) klist[count] = i;
      count++;
      if (count == 300) goto done;
      const ulonglong2* rp = (const ulonglong2*)(mask + (size_t)i * 128);
      ulonglong2 rv = rp[lane];
      Sx |= rv.x;
      Sy |= rv.y;
      u64 cur2 = __shfl((w2 & 1) ? Sy : Sx, w2 >> 1);
      rem &= ~cur2;
      rem &= (b == 63) ? 0ull : (~0ull << (b + 1));
    }
  }
done:
  __syncthreads();
  for (int j = lane; j < 300; j += 64) {
    float s;
    float4 bb;
    if (j < count) {
      int i = klist[j];
      s = sortedS[i];
      bb = sortedB[i];
    } else {
      s = -1.f;
      bb = make_float4(-1.f, -1.f, -1.f, -1.f);
    }
    out[j * 5 + 0] = s;
    out[j * 5 + 1] = bb.x;
    out[j * 5 + 2] = bb.y;
    out[j * 5 + 3] = bb.z;
    out[j * 5 + 4] = bb.w;
  }
}

// ---------------- workspace layout (bytes) ----------------------------------
constexpr size_t O_XH = 0;                // 8,921,088   xpadT hi
constexpr size_t O_XL = 8921088;          // 8,921,088   xpadT lo
constexpr size_t O_WTH = 17842176;        // 18,874,368  wT hi
constexpr size_t O_WTL = 36716544;        // 18,874,368  wT lo
constexpr size_t O_HH = 55590912;         // 8,388,608   h hi
constexpr size_t O_HL = 63979520;         // 8,388,608   h lo
constexpr size_t O_WHH = 72368128;        // 262,144     head w hi
constexpr size_t O_WHL = 72630272;        // 262,144     head w lo
constexpr size_t O_BHD = 72892416;        // 512         head bias
constexpr size_t O_SC = 72892928;         // 245,760     scores
constexpr size_t O_BX = 73138688;         // 983,040     boxes (float4)
constexpr size_t O_KEY = 74121728;        // 245,760     key32
constexpr size_t O_HIST = 74367488;       // 262,144     histogram
constexpr size_t O_CNT = 74629632;        // 256         atomic counter
constexpr size_t O_CAND = 74629888;       // 65,536      candidates
constexpr size_t O_SELT = 74695424;       // 256         T16
constexpr size_t O_SS = 74695680;         // 24,064      sorted scores [6016]
constexpr size_t O_SB = 74719744;         // 96,256      sorted boxes  [6016]
// aliases (regions dead by the time these are written):
constexpr size_t O_RAW = 0;               // 2,097,152  raw head out (aliases xpadT, dead after conv GEMM)
constexpr size_t O_MASK = 17842176;       // 6,160,384  NMS mask (aliases wT, dead after conv GEMM)
// total distinct footprint ~74.8 MB

extern "C" void kernel_launch(void* const* d_in, const int* in_sizes, int n_in,
                              void* d_out, int out_size, void* d_ws,
                              size_t ws_size, hipStream_t stream) {
  (void)in_sizes; (void)n_in; (void)out_size; (void)ws_size;
  const float* x = (const float*)d_in[1];
  const float* conv_w = (const float*)d_in[2];
  const float* conv_b = (const float*)d_in[3];
  const float* score_w = (const float*)d_in[4];
  const float* score_b = (const float*)d_in[5];
  const float* loc_w = (const float*)d_in[6];
  const float* loc_b = (const float*)d_in[7];
  float* out = (float*)d_out;
  char* ws = (char*)d_ws;

  ushort* xh = (ushort*)(ws + O_XH);
  ushort* xl = (ushort*)(ws + O_XL);
  ushort* wTh = (ushort*)(ws + O_WTH);
  ushort* wTl = (ushort*)(ws + O_WTL);
  ushort* hh = (ushort*)(ws + O_HH);
  ushort* hl = (ushort*)(ws + O_HL);
  ushort* wHh = (ushort*)(ws + O_WHH);
  ushort* wHl = (ushort*)(ws + O_WHL);
  float* biasH = (float*)(ws + O_BHD);
  float* raw = (float*)(ws + O_RAW);
  float* scores = (float*)(ws + O_SC);
  float4* boxes = (float4*)(ws + O_BX);
  uint* key32 = (uint*)(ws + O_KEY);
  uint* hist = (uint*)(ws + O_HIST);
  uint* cnt = (uint*)(ws + O_CNT);
  u64* cand = (u64*)(ws + O_CAND);
  uint* selT = (uint*)(ws + O_SELT);
  float* sortedS = (float*)(ws + O_SS);
  float4* sortedB = (float4*)(ws + O_SB);
  u64* mask = (u64*)(ws + O_MASK);

  // zero the padded-input borders (whole buffer) and histogram+counter
  hipMemsetAsync(ws + O_XH, 0, 2 * 8921088, stream);
  hipMemsetAsync(ws + O_HIST, 0, 262144 + 256, stream);

  prep_x<<<dim3(16, 64), 256, 0, stream>>>(x, xh, xl);
  prep_w<<<dim3(1024, 4), 256, 0, stream>>>(conv_w, wTh, wTl);
  prep_head<<<512, 256, 0, stream>>>(score_w, loc_w, score_b, loc_b, wHh, wHl, biasH);

  // conv: M=4096, N=1024, K=9*1024 -> h (relu, bf16 hi/lo); tile 128x64,
  // grid (32,16)=512 blocks -> 2 blocks/CU; K order bit-identical to round 0
  gemm_bf16x3<1, 64><<<dim3(32, 16), 256, 0, stream>>>(xh, xl, wTh, wTl, conv_b,
                                                       288, nullptr, hh, hl);
  // heads: M=4096, N=128(pad), K=1024 -> raw f32 (tile 128x128, as round 0)
  gemm_bf16x3<0, 128><<<dim3(32, 1), 256, 0, stream>>>(hh, hl, wHh, wHl, biasH,
                                                       32, raw, nullptr, nullptr);

  decode_k<<<240, 256, 0, stream>>>(raw, scores, boxes, key32, hist);
  find_t16<<<1, 256, 0, stream>>>(hist, selT);
  gather_k<<<240, 256, 0, stream>>>(key32, selT, cnt, cand);
  sort_gather<<<1, 1024, 65536, stream>>>(cand, cnt, scores, boxes, sortedS, sortedB);
  iou_mask<<<dim3(94, 94), 64, 0, stream>>>(sortedB, mask);
  nms_scan<<<1, 64, 0, stream>>>(mask, sortedS, sortedB, out);
}

// Round 6
// 723.249 us; speedup vs baseline: 1.3106x; 1.3106x over previous
//
#include <hip/hip_runtime.h>

typedef unsigned int uint;
typedef unsigned short ushort;
typedef unsigned long long u64;

typedef __attribute__((ext_vector_type(8))) short short8;
typedef __attribute__((ext_vector_type(4))) float floatx4;

// ---------------- helpers ----------------
__device__ inline ushort bf16rne(float v) {
  uint b = __float_as_uint(v);
  uint r = (b + 0x7fffu + ((b >> 16) & 1u)) >> 16;
  return (ushort)r;
}

__device__ inline void gl_lds16(const void* g, void* l) {
  __builtin_amdgcn_global_load_lds(
      (const __attribute__((address_space(1))) unsigned int*)g,
      (__attribute__((address_space(3))) unsigned int*)l, 16, 0, 0);
}

// ======================= chunk-seg-major global layouts =====================
// All GEMM-staged arrays are stored so that the seg-major LDS stage (slot
// L -> row=L%R, seg=L/R; proven 0-bank-conflict in round 5) reads CONTIGUOUS
// global bytes per wave (round 5's 484us regression was 16B-per-2048B-stride
// staging; FETCH stayed flat but VMEM/L2 requests x4).
//   xpadT: [cc 32][seg 4][spatial 66*66][8e]   (ci = cc*32 + seg*8 + e)
//   wT:    [off*32+cc][seg 4][co 1024][8e]
//   h:     [cc 32][seg 4][m 4096][8e]
//   wH:    [cc 32][seg 4][o 128][8e]
// Sizes identical to the flat layouts (pure bijection) -> workspace unchanged.

// ---------------- prep: x -> padded transposed bf16 hi/lo -------------------
__global__ __launch_bounds__(256) void prep_x(const float* __restrict__ x,
                                              ushort* __restrict__ xh,
                                              ushort* __restrict__ xl) {
  __shared__ float tile[64 * 65];
  int ci0 = blockIdx.x * 64, y = blockIdx.y, t = threadIdx.x;
#pragma unroll
  for (int it = 0; it < 16; ++it) {
    int L = t + 256 * it;
    int cl = L >> 6, xx = L & 63;
    tile[cl * 65 + xx] = x[(size_t)(ci0 + cl) * 4096 + y * 64 + xx];
  }
  __syncthreads();
#pragma unroll
  for (int it = 0; it < 16; ++it) {
    int L = t + 256 * it;
    int xx = L >> 6, cl = L & 63;
    float v = tile[cl * 65 + xx];
    ushort h2 = bf16rne(v);
    float hf = __uint_as_float((uint)h2 << 16);
    ushort l2 = bf16rne(v - hf);
    int ci = ci0 + cl;
    int cc = ci >> 5, sg = (ci >> 3) & 3, e = ci & 7;
    size_t oi = ((size_t)(cc * 4 + sg) * 4356 + (y + 1) * 66 + (xx + 1)) * 8 + e;
    xh[oi] = h2;
    xl[oi] = l2;
  }
}

// ---------------- prep: conv_w[co][ci][3][3] -> wT chunk-seg-major ----------
__global__ __launch_bounds__(256) void prep_w(const float* __restrict__ w,
                                              ushort* __restrict__ wh,
                                              ushort* __restrict__ wl) {
  __shared__ float tile[2304];  // 256 ci x 9 off
  int co = blockIdx.x, ci0 = blockIdx.y * 256, t = threadIdx.x;
  const float* src = w + ((size_t)co * 1024 + ci0) * 9;
  for (int i = t; i < 2304; i += 256) tile[i] = src[i];
  __syncthreads();
  int ci = ci0 + t;
  int cc = ci >> 5, sg = (ci >> 3) & 3, e = ci & 7;
#pragma unroll
  for (int off = 0; off < 9; ++off) {
    float v = tile[t * 9 + off];
    ushort h2 = bf16rne(v);
    float hf = __uint_as_float((uint)h2 << 16);
    ushort l2 = bf16rne(v - hf);
    size_t oi = (((size_t)(off * 32 + cc) * 4 + sg) * 1024 + co) * 8 + e;
    wh[oi] = h2;
    wl[oi] = l2;
  }
}

// ---------------- prep: head weights -> wH chunk-seg-major + bias[128] ------
__global__ __launch_bounds__(256) void prep_head(
    const float* __restrict__ score_w, const float* __restrict__ loc_w,
    const float* __restrict__ score_b, const float* __restrict__ loc_b,
    ushort* __restrict__ wh, ushort* __restrict__ wl, float* __restrict__ bh) {
  int idx = blockIdx.x * 256 + threadIdx.x;  // < 131072
  int o = idx >> 10, ci = idx & 1023;
  float v = 0.f;
  if (o < 15) v = score_w[o * 1024 + ci];
  else if (o < 75) v = loc_w[(o - 15) * 1024 + ci];
  ushort h2 = bf16rne(v);
  float hf = __uint_as_float((uint)h2 << 16);
  int cc = ci >> 5, sg = (ci >> 3) & 3, e = ci & 7;
  size_t oi = ((size_t)(cc * 4 + sg) * 128 + o) * 8 + e;
  wh[oi] = h2;
  wl[oi] = bf16rne(v - hf);
  if (idx < 128) bh[idx] = (idx < 15) ? score_b[idx] : ((idx < 75) ? loc_b[idx - 15] : 0.f);
}

// ---------------- bf16x3 GEMM: C[m][n] = sum_k A[m][k]*B[n][k] --------------
// Tile 128 x BN, 256 threads (4 waves). K-accumulation order BIT-IDENTICAL to
// round 0/5 (sequential chunks, hh/hl/lh MFMA order) -- split-K reordering
// flips a knife-edge NMS decision (3x absmax=720).
// BN=64 conv: grid (32,16)=512 blocks -> 2 blocks/CU; same-A blocks share XCD.
// LDS: seg-major [4 k-octets][rows][16B] per section -> 0 bank conflicts
// (measured round 5). Globals are chunk-seg-major (above) -> each wave's
// stage reads 1024 CONTIGUOUS bytes (fixes round 5's staging amplification).
template <int IM2COL, int BN>
__global__ __launch_bounds__(256, 1) void gemm_bf16x3(
    const ushort* __restrict__ Ahi, const ushort* __restrict__ Alo,
    const ushort* __restrict__ Bhi, const ushort* __restrict__ Blo,
    const float* __restrict__ bias, int nChunks, float* __restrict__ outRaw,
    ushort* __restrict__ outHi, ushort* __restrict__ outLo) {
  constexpr int ASEC = 128 * 32;       // ushorts per A section
  constexpr int BSEC = BN * 32;        // ushorts per B section
  constexpr int BUFU = 2 * ASEC + 2 * BSEC;  // ushorts per buffer
  constexpr int NJ = BN / 32;          // n-fragments per wave
  __shared__ ushort sm[2 * BUFU];      // BN=128: 64KB, BN=64: 48KB
  const int t = threadIdx.x;
  const int m0 = blockIdx.x * 128;
  const int n0 = blockIdx.y * BN;

  auto stage = [&](int c, int bufIdx) {
    ushort* secAh = sm + bufIdx * BUFU;
    ushort* secAl = secAh + ASEC;
    ushort* secBh = secAl + ASEC;
    ushort* secBl = secBh + BSEC;
    int off = 0, cc = 0, oy = 0, ox = 0;
    if (IM2COL) {
      off = c >> 5;   // 0..8  (ky*3+kx)
      cc = c & 31;    // ci chunk
      oy = off / 3;
      ox = off - 3 * oy;
    }
    // A: 512 slots, seg-major (row = L&127, seg = L>>7); wave = 1KB contig
#pragma unroll
    for (int q = 0; q < 2; ++q) {
      int L = t + 256 * q;
      int row = L & 127, seg = L >> 7;
      size_t aoff;
      if (IM2COL) {
        int m = m0 + row, y = m >> 6, xq = m & 63;
        aoff = ((size_t)(cc * 4 + seg) * 4356 + (y + oy) * 66 + (xq + ox)) * 16;
      } else {
        aoff = ((size_t)(c * 4 + seg) * 4096 + (m0 + row)) * 16;
      }
      gl_lds16((const char*)Ahi + aoff, (char*)secAh + L * 16);
      gl_lds16((const char*)Alo + aoff, (char*)secAl + L * 16);
    }
    // B: BN*4 slots, seg-major (row = L%BN, seg = L/BN); wave = 1KB contig
#pragma unroll
    for (int q = 0; q < BN / 64; ++q) {
      int L = t + 256 * q;
      int row = L % BN, seg = L / BN;
      size_t boff;
      if (IM2COL) {
        boff = (((size_t)(off * 32 + cc) * 4 + seg) * 1024 + (n0 + row)) * 16;
      } else {
        boff = ((size_t)(c * 4 + seg) * 128 + (n0 + row)) * 16;
      }
      gl_lds16((const char*)Bhi + boff, (char*)secBh + L * 16);
      gl_lds16((const char*)Blo + boff, (char*)secBl + L * 16);
    }
  };

  const int lane = t & 63, wv = t >> 6;
  const int wm = (wv & 1) * 64, wn = (wv >> 1) * (BN / 2);
  const int rA = wm + (lane & 15);
  const int rB = wn + (lane & 15);
  const int segA = (lane >> 4) * 2048;      // A seg region base (bytes)
  const int segB = (lane >> 4) * (BN * 16); // B seg region base (bytes)

  floatx4 acc[4][NJ];
#pragma unroll
  for (int i = 0; i < 4; ++i)
#pragma unroll
    for (int j = 0; j < NJ; ++j) acc[i][j] = (floatx4){0.f, 0.f, 0.f, 0.f};

  stage(0, 0);
  for (int kc = 0; kc < nChunks; ++kc) {
    __syncthreads();  // staged chunk kc landed; prev compute done
    if (kc + 1 < nChunks) stage(kc + 1, (kc + 1) & 1);  // overlap with compute
    const ushort* sb = sm + (kc & 1) * BUFU;
    const char* cAh = (const char*)sb;
    const char* cAl = (const char*)(sb + ASEC);
    const char* cBh = (const char*)(sb + 2 * ASEC);
    const char* cBl = (const char*)(sb + 2 * ASEC + BSEC);
    short8 ah[4], al[4], bh2[NJ], bl2[NJ];
#pragma unroll
    for (int i = 0; i < 4; ++i) {
      int pa = segA + (rA + 16 * i) * 16;
      ah[i] = *(const short8*)(cAh + pa);
      al[i] = *(const short8*)(cAl + pa);
    }
#pragma unroll
    for (int j = 0; j < NJ; ++j) {
      int pb = segB + (rB + 16 * j) * 16;
      bh2[j] = *(const short8*)(cBh + pb);
      bl2[j] = *(const short8*)(cBl + pb);
    }
#pragma unroll
    for (int i = 0; i < 4; ++i)
#pragma unroll
      for (int j = 0; j < NJ; ++j) {
        acc[i][j] = __builtin_amdgcn_mfma_f32_16x16x32_bf16(ah[i], bh2[j], acc[i][j], 0, 0, 0);
        acc[i][j] = __builtin_amdgcn_mfma_f32_16x16x32_bf16(ah[i], bl2[j], acc[i][j], 0, 0, 0);
        acc[i][j] = __builtin_amdgcn_mfma_f32_16x16x32_bf16(al[i], bh2[j], acc[i][j], 0, 0, 0);
      }
  }

#pragma unroll
  for (int i = 0; i < 4; ++i)
#pragma unroll
    for (int j = 0; j < NJ; ++j) {
      int nn = n0 + wn + 16 * j + (lane & 15);
      float bv = bias[nn];
#pragma unroll
      for (int r = 0; r < 4; ++r) {
        int mm = m0 + wm + 16 * i + (lane >> 4) * 4 + r;  // C: row=(lane>>4)*4+reg
        float v = acc[i][j][r] + bv;
        if (IM2COL) {
          v = fmaxf(v, 0.f);
          ushort h2 = bf16rne(v);
          float hf = __uint_as_float((uint)h2 << 16);
          ushort l2 = bf16rne(v - hf);
          int cc = nn >> 5, sg = (nn >> 3) & 3, e = nn & 7;
          size_t ho = ((size_t)(cc * 4 + sg) * 4096 + mm) * 8 + e;  // h layout
          outHi[ho] = h2;
          outLo[ho] = l2;
        } else {
          outRaw[(size_t)mm * 128 + nn] = v;
        }
      }
    }
}

// ---------------- decode + key + histogram ----------------------------------
__global__ __launch_bounds__(256) void decode_k(const float* __restrict__ raw,
                                                float* __restrict__ scores,
                                                float4* __restrict__ boxes,
                                                uint* __restrict__ key32,
                                                uint* __restrict__ hist) {
  int i = blockIdx.x * 256 + threadIdx.x;  // exactly 61440
  int m = i / 15, a = i - m * 15;
  int y = m >> 6, x = m & 63;
  const float* rp = raw + (size_t)m * 128;
  float logit = rp[a];
  float dx = rp[15 + 4 * a], dy = rp[16 + 4 * a];
  float dw = rp[17 + 4 * a], dh = rp[18 + 4 * a];
  int rr = a / 5, ss = a - rr * 5;
  float sc5 = (float)(2 << ss);
  float W = ((rr == 0) ? 23.f : (rr == 1) ? 16.f : 11.f) * sc5;
  float H = ((rr == 0) ? 12.f : (rr == 1) ? 16.f : 22.f) * sc5;
  float aw = W - 1.f, ah = H - 1.f;
  float ax = x * 16.f + 7.5f, ay = y * 16.f + 7.5f;
  float ox = dx * aw + ax, oyc = dy * ah + ay;
  float ow = expf(fminf(dw, 4.14f)) * aw * 0.5f;
  float oh = expf(fminf(dh, 4.14f)) * ah * 0.5f;
  float x1 = fminf(fmaxf(ox - ow, 0.f), 1023.f);
  float y1 = fminf(fmaxf(oyc - oh, 0.f), 1023.f);
  float x2 = fminf(fmaxf(ox + ow, 0.f), 1023.f);
  float y2 = fminf(fmaxf(oyc + oh, 0.f), 1023.f);
  bool inval = ((x2 - x1) < 16.f) || ((y2 - y1) < 16.f);
  float sc = inval ? -1.f : (1.f / (1.f + expf(-logit)));
  scores[i] = sc;
  boxes[i] = inval ? make_float4(-1.f, -1.f, -1.f, -1.f) : make_float4(x1, y1, x2, y2);
  uint kb = __float_as_uint(sc);
  uint key = (kb & 0x80000000u) ? ~kb : (kb | 0x80000000u);
  key32[i] = key;
  atomicAdd(&hist[key >> 16], 1u);
}

// ---------------- find 16-bit prefix threshold for top-6000 -----------------
__global__ __launch_bounds__(256) void find_t16(const uint* __restrict__ hist,
                                                uint* __restrict__ selT) {
  __shared__ uint ps[256];
  __shared__ int segS;
  int t = threadIdx.x;
  uint s = 0;
  const uint* hp = hist + t * 256;
  for (int i = 0; i < 256; ++i) s += hp[i];
  ps[t] = s;
  __syncthreads();
  for (int d = 1; d < 256; d <<= 1) {
    uint v = ps[t] + ((t + d < 256) ? ps[t + d] : 0u);
    __syncthreads();
    ps[t] = v;
    __syncthreads();
  }
  if (ps[t] >= 6000u && (t == 255 || ps[t + 1] < 6000u)) segS = t;
  __syncthreads();
  int sg = segS;
  uint base = (sg == 255) ? 0u : ps[sg + 1];
  uint h2 = hist[sg * 256 + t];
  __syncthreads();
  ps[t] = h2;
  __syncthreads();
  for (int d = 1; d < 256; d <<= 1) {
    uint v = ps[t] + ((t + d < 256) ? ps[t + d] : 0u);
    __syncthreads();
    ps[t] = v;
    __syncthreads();
  }
  if (base + ps[t] >= 6000u && (t == 255 || base + ps[t + 1] < 6000u))
    *selT = (uint)(sg * 256 + t);
}

// ---------------- gather candidates (prefix >= T16) -------------------------
__global__ __launch_bounds__(256) void gather_k(const uint* __restrict__ key32,
                                                const uint* __restrict__ selT,
                                                uint* __restrict__ cnt,
                                                u64* __restrict__ cand) {
  int i = blockIdx.x * 256 + threadIdx.x;  // exactly 61440
  uint T = *selT;
  uint k = key32[i];
  if ((k >> 16) >= T) {
    uint pos = atomicAdd(cnt, 1u);
    if (pos < 8192) cand[pos] = ((u64)k << 32) | (u64)(~(uint)i);
  }
}

// ---------------- single-block bitonic sort (desc) + gather top-6000 --------
__global__ __launch_bounds__(1024) void sort_gather(
    const u64* __restrict__ cand, const uint* __restrict__ cnt,
    const float* __restrict__ scores, const float4* __restrict__ boxes,
    float* __restrict__ sortedS, float4* __restrict__ sortedB) {
  extern __shared__ u64 sk[];  // 8192 * 8 = 64 KB
  int t = threadIdx.x;
  int C = (int)*cnt;
  if (C > 8192) C = 8192;
  for (int j = t; j < 8192; j += 1024) sk[j] = (j < C) ? cand[j] : 0ull;
  __syncthreads();
  for (int k = 2; k <= 8192; k <<= 1) {
    for (int j2 = k >> 1; j2 > 0; j2 >>= 1) {
      for (int p = t; p < 4096; p += 1024) {
        int i = ((p & ~(j2 - 1)) << 1) | (p & (j2 - 1));
        int ix = i | j2;
        u64 a = sk[i], b = sk[ix];
        bool ddir = (i & k) != 0;
        if ((a < b) != ddir) { sk[i] = b; sk[ix] = a; }
      }
      __syncthreads();
    }
  }
  for (int j = t; j < 6016; j += 1024) {
    if (j < 6000) {
      u64 key = sk[j];
      uint idx = ~(uint)(key & 0xffffffffu);
      sortedS[j] = scores[idx];
      sortedB[j] = boxes[idx];
    } else {
      sortedS[j] = -1.f;
      sortedB[j] = make_float4(0.f, 0.f, 0.f, 0.f);
    }
  }
}

// ---------------- IoU suppression bitmask: mask[row][128 u64 words] ---------
__global__ __launch_bounds__(64) void iou_mask(const float4* __restrict__ boxes,
                                               u64* __restrict__ mask) {
  __shared__ float cx1[64], cy1[64], cx2[64], cy2[64], car[64];
  int bi = blockIdx.x, bj = blockIdx.y, t = threadIdx.x;
  float4 cb = boxes[bj * 64 + t];
  cx1[t] = cb.x; cy1[t] = cb.y; cx2[t] = cb.z; cy2[t] = cb.w;
  car[t] = (cb.z - cb.x) * (cb.w - cb.y);
  __syncthreads();
  int r = bi * 64 + t;
  float4 rb = boxes[r];
  float ra = (rb.z - rb.x) * (rb.w - rb.y);
  u64 wd = 0;
#pragma unroll 8
  for (int j = 0; j < 64; ++j) {
    float iw = fmaxf(fminf(rb.z, cx2[j]) - fmaxf(rb.x, cx1[j]), 0.f);
    float ih = fmaxf(fminf(rb.w, cy2[j]) - fmaxf(rb.y, cy1[j]), 0.f);
    float inter = iw * ih;
    float iou = inter / (ra + car[j] - inter + 1e-12f);
    if (iou > 0.7f && r != bj * 64 + j) wd |= (1ull << j);
  }
  mask[(size_t)r * 128 + bj] = wd;
}

// ---------------- serial NMS scan (1 wave), word-skipping, early stop -------
__global__ __launch_bounds__(64) void nms_scan(const u64* __restrict__ mask,
                                               const float* __restrict__ sortedS,
                                               const float4* __restrict__ sortedB,
                                               float* __restrict__ out) {
  __shared__ int klist[300];
  int lane = threadIdx.x;
  u64 Sx = 0, Sy = 0;  // lane l owns suppression words 2l and 2l+1
  for (int w2 = 0; w2 < 94; ++w2) {
    bool neg = sortedS[w2 * 64 + lane] < 0.f;
    u64 m2 = __ballot(neg);
    if ((w2 >> 1) == lane) { if (w2 & 1) Sy = m2; else Sx = m2; }
  }
  int count = 0;
  for (int w2 = 0; w2 < 94; ++w2) {
    u64 cur = __shfl((w2 & 1) ? Sy : Sx, w2 >> 1);
    u64 rem = ~cur;
    if (w2 == 93) rem &= (1ull << 48) - 1;  // rows 6000..6015 are pad
    while (rem) {
      int b = __builtin_ctzll(rem);
      int i = w2 * 64 + b;
      if (lane == 0) klist[count] = i;
      count++;
      if (count == 300) goto done;
      const ulonglong2* rp = (const ulonglong2*)(mask + (size_t)i * 128);
      ulonglong2 rv = rp[lane];
      Sx |= rv.x;
      Sy |= rv.y;
      u64 cur2 = __shfl((w2 & 1) ? Sy : Sx, w2 >> 1);
      rem &= ~cur2;
      rem &= (b == 63) ? 0ull : (~0ull << (b + 1));
    }
  }
done:
  __syncthreads();
  for (int j = lane; j < 300; j += 64) {
    float s;
    float4 bb;
    if (j < count) {
      int i = klist[j];
      s = sortedS[i];
      bb = sortedB[i];
    } else {
      s = -1.f;
      bb = make_float4(-1.f, -1.f, -1.f, -1.f);
    }
    out[j * 5 + 0] = s;
    out[j * 5 + 1] = bb.x;
    out[j * 5 + 2] = bb.y;
    out[j * 5 + 3] = bb.z;
    out[j * 5 + 4] = bb.w;
  }
}

// ---------------- workspace layout (bytes) ----------------------------------
constexpr size_t O_XH = 0;                // 8,921,088   xpadT hi
constexpr size_t O_XL = 8921088;          // 8,921,088   xpadT lo
constexpr size_t O_WTH = 17842176;        // 18,874,368  wT hi
constexpr size_t O_WTL = 36716544;        // 18,874,368  wT lo
constexpr size_t O_HH = 55590912;         // 8,388,608   h hi
constexpr size_t O_HL = 63979520;         // 8,388,608   h lo
constexpr size_t O_WHH = 72368128;        // 262,144     head w hi
constexpr size_t O_WHL = 72630272;        // 262,144     head w lo
constexpr size_t O_BHD = 72892416;        // 512         head bias
constexpr size_t O_SC = 72892928;         // 245,760     scores
constexpr size_t O_BX = 73138688;         // 983,040     boxes (float4)
constexpr size_t O_KEY = 74121728;        // 245,760     key32
constexpr size_t O_HIST = 74367488;       // 262,144     histogram
constexpr size_t O_CNT = 74629632;        // 256         atomic counter
constexpr size_t O_CAND = 74629888;       // 65,536      candidates
constexpr size_t O_SELT = 74695424;       // 256         T16
constexpr size_t O_SS = 74695680;         // 24,064      sorted scores [6016]
constexpr size_t O_SB = 74719744;         // 96,256      sorted boxes  [6016]
// aliases (regions dead by the time these are written):
constexpr size_t O_RAW = 0;               // 2,097,152  raw head out (aliases xpadT, dead after conv GEMM)
constexpr size_t O_MASK = 17842176;       // 6,160,384  NMS mask (aliases wT, dead after conv GEMM)
// total distinct footprint ~74.8 MB

extern "C" void kernel_launch(void* const* d_in, const int* in_sizes, int n_in,
                              void* d_out, int out_size, void* d_ws,
                              size_t ws_size, hipStream_t stream) {
  (void)in_sizes; (void)n_in; (void)out_size; (void)ws_size;
  const float* x = (const float*)d_in[1];
  const float* conv_w = (const float*)d_in[2];
  const float* conv_b = (const float*)d_in[3];
  const float* score_w = (const float*)d_in[4];
  const float* score_b = (const float*)d_in[5];
  const float* loc_w = (const float*)d_in[6];
  const float* loc_b = (const float*)d_in[7];
  float* out = (float*)d_out;
  char* ws = (char*)d_ws;

  ushort* xh = (ushort*)(ws + O_XH);
  ushort* xl = (ushort*)(ws + O_XL);
  ushort* wTh = (ushort*)(ws + O_WTH);
  ushort* wTl = (ushort*)(ws + O_WTL);
  ushort* hh = (ushort*)(ws + O_HH);
  ushort* hl = (ushort*)(ws + O_HL);
  ushort* wHh = (ushort*)(ws + O_WHH);
  ushort* wHl = (ushort*)(ws + O_WHL);
  float* biasH = (float*)(ws + O_BHD);
  float* raw = (float*)(ws + O_RAW);
  float* scores = (float*)(ws + O_SC);
  float4* boxes = (float4*)(ws + O_BX);
  uint* key32 = (uint*)(ws + O_KEY);
  uint* hist = (uint*)(ws + O_HIST);
  uint* cnt = (uint*)(ws + O_CNT);
  u64* cand = (u64*)(ws + O_CAND);
  uint* selT = (uint*)(ws + O_SELT);
  float* sortedS = (float*)(ws + O_SS);
  float4* sortedB = (float4*)(ws + O_SB);
  u64* mask = (u64*)(ws + O_MASK);

  // zero the padded-input borders (whole buffer) and histogram+counter
  hipMemsetAsync(ws + O_XH, 0, 2 * 8921088, stream);
  hipMemsetAsync(ws + O_HIST, 0, 262144 + 256, stream);

  prep_x<<<dim3(16, 64), 256, 0, stream>>>(x, xh, xl);
  prep_w<<<dim3(1024, 4), 256, 0, stream>>>(conv_w, wTh, wTl);
  prep_head<<<512, 256, 0, stream>>>(score_w, loc_w, score_b, loc_b, wHh, wHl, biasH);

  // conv: M=4096, N=1024, K=9*1024 -> h (relu, bf16 hi/lo); tile 128x64,
  // grid (32,16)=512 blocks -> 2 blocks/CU; K order bit-identical to round 0
  gemm_bf16x3<1, 64><<<dim3(32, 16), 256, 0, stream>>>(xh, xl, wTh, wTl, conv_b,
                                                       288, nullptr, hh, hl);
  // heads: M=4096, N=128(pad), K=1024 -> raw f32 (tile 128x128)
  gemm_bf16x3<0, 128><<<dim3(32, 1), 256, 0, stream>>>(hh, hl, wHh, wHl, biasH,
                                                       32, raw, nullptr, nullptr);

  decode_k<<<240, 256, 0, stream>>>(raw, scores, boxes, key32, hist);
  find_t16<<<1, 256, 0, stream>>>(hist, selT);
  gather_k<<<240, 256, 0, stream>>>(key32, selT, cnt, cand);
  sort_gather<<<1, 1024, 65536, stream>>>(cand, cnt, scores, boxes, sortedS, sortedB);
  iou_mask<<<dim3(94, 94), 64, 0, stream>>>(sortedB, mask);
  nms_scan<<<1, 64, 0, stream>>>(mask, sortedS, sortedB, out);
}

// Round 7
// 722.897 us; speedup vs baseline: 1.3112x; 1.0005x over previous
//
#include <hip/hip_runtime.h>

typedef unsigned int uint;
typedef unsigned short ushort;
typedef unsigned long long u64;

typedef __attribute__((ext_vector_type(8))) short short8;
typedef __attribute__((ext_vector_type(4))) float floatx4;

// ---------------- helpers ----------------
__device__ inline ushort bf16rne(float v) {
  uint b = __float_as_uint(v);
  uint r = (b + 0x7fffu + ((b >> 16) & 1u)) >> 16;
  return (ushort)r;
}

__device__ inline void gl_lds16(const void* g, void* l) {
  __builtin_amdgcn_global_load_lds(
      (const __attribute__((address_space(1))) unsigned int*)g,
      (__attribute__((address_space(3))) unsigned int*)l, 16, 0, 0);
}

// ======================= chunk-seg-major global layouts =====================
// All GEMM-staged arrays are stored so that the seg-major LDS stage (slot
// L -> row=L%R, seg=L/R; 0 bank conflicts, measured round 5/6) reads
// CONTIGUOUS global bytes per wave (measured round 6: conv 484 -> 209us).
//   xpadT: [cc 32][seg 4][spatial 66*66][8e]   (ci = cc*32 + seg*8 + e)
//   wT:    [off*32+cc][seg 4][co 1024][8e]
//   h:     [cc 32][seg 4][m 4096][8e]
//   wH:    [cc 32][seg 4][o 128][8e]

// ---------------- prep: x -> padded transposed bf16 hi/lo -------------------
__global__ __launch_bounds__(256) void prep_x(const float* __restrict__ x,
                                              ushort* __restrict__ xh,
                                              ushort* __restrict__ xl) {
  __shared__ float tile[64 * 65];
  int ci0 = blockIdx.x * 64, y = blockIdx.y, t = threadIdx.x;
#pragma unroll
  for (int it = 0; it < 16; ++it) {
    int L = t + 256 * it;
    int cl = L >> 6, xx = L & 63;
    tile[cl * 65 + xx] = x[(size_t)(ci0 + cl) * 4096 + y * 64 + xx];
  }
  __syncthreads();
#pragma unroll
  for (int it = 0; it < 16; ++it) {
    int L = t + 256 * it;
    int xx = L >> 6, cl = L & 63;
    float v = tile[cl * 65 + xx];
    ushort h2 = bf16rne(v);
    float hf = __uint_as_float((uint)h2 << 16);
    ushort l2 = bf16rne(v - hf);
    int ci = ci0 + cl;
    int cc = ci >> 5, sg = (ci >> 3) & 3, e = ci & 7;
    size_t oi = ((size_t)(cc * 4 + sg) * 4356 + (y + 1) * 66 + (xx + 1)) * 8 + e;
    xh[oi] = h2;
    xl[oi] = l2;
  }
}

// ---------------- prep: conv_w[co][ci][3][3] -> wT chunk-seg-major ----------
__global__ __launch_bounds__(256) void prep_w(const float* __restrict__ w,
                                              ushort* __restrict__ wh,
                                              ushort* __restrict__ wl) {
  __shared__ float tile[2304];  // 256 ci x 9 off
  int co = blockIdx.x, ci0 = blockIdx.y * 256, t = threadIdx.x;
  const float* src = w + ((size_t)co * 1024 + ci0) * 9;
  for (int i = t; i < 2304; i += 256) tile[i] = src[i];
  __syncthreads();
  int ci = ci0 + t;
  int cc = ci >> 5, sg = (ci >> 3) & 3, e = ci & 7;
#pragma unroll
  for (int off = 0; off < 9; ++off) {
    float v = tile[t * 9 + off];
    ushort h2 = bf16rne(v);
    float hf = __uint_as_float((uint)h2 << 16);
    ushort l2 = bf16rne(v - hf);
    size_t oi = (((size_t)(off * 32 + cc) * 4 + sg) * 1024 + co) * 8 + e;
    wh[oi] = h2;
    wl[oi] = l2;
  }
}

// ---------------- prep: head weights -> wH chunk-seg-major + bias[128] ------
__global__ __launch_bounds__(256) void prep_head(
    const float* __restrict__ score_w, const float* __restrict__ loc_w,
    const float* __restrict__ score_b, const float* __restrict__ loc_b,
    ushort* __restrict__ wh, ushort* __restrict__ wl, float* __restrict__ bh) {
  int idx = blockIdx.x * 256 + threadIdx.x;  // < 131072
  int o = idx >> 10, ci = idx & 1023;
  float v = 0.f;
  if (o < 15) v = score_w[o * 1024 + ci];
  else if (o < 75) v = loc_w[(o - 15) * 1024 + ci];
  ushort h2 = bf16rne(v);
  float hf = __uint_as_float((uint)h2 << 16);
  int cc = ci >> 5, sg = (ci >> 3) & 3, e = ci & 7;
  size_t oi = ((size_t)(cc * 4 + sg) * 128 + o) * 8 + e;
  wh[oi] = h2;
  wl[oi] = bf16rne(v - hf);
  if (idx < 128) bh[idx] = (idx < 15) ? score_b[idx] : ((idx < 75) ? loc_b[idx - 15] : 0.f);
}

// ---------------- bf16x3 GEMM: C[m][n] = sum_k A[m][k]*B[n][k] --------------
// Tile 128 x BN, 256 threads (4 waves). K-accumulation order BIT-IDENTICAL to
// round 0 (sequential chunks, hh/hl/lh MFMA order) -- split-K reordering
// flips a knife-edge NMS decision (3x absmax=720).
// BN=64 conv: grid (32,16)=512 blocks -> 2 blocks/CU.
// LDS: seg-major [4 k-octets][rows][16B] per section -> 0 bank conflicts.
// Globals chunk-seg-major -> each wave's stage reads 1024 contiguous bytes.
template <int IM2COL, int BN>
__global__ __launch_bounds__(256, 1) void gemm_bf16x3(
    const ushort* __restrict__ Ahi, const ushort* __restrict__ Alo,
    const ushort* __restrict__ Bhi, const ushort* __restrict__ Blo,
    const float* __restrict__ bias, int nChunks, float* __restrict__ outRaw,
    ushort* __restrict__ outHi, ushort* __restrict__ outLo) {
  constexpr int ASEC = 128 * 32;       // ushorts per A section
  constexpr int BSEC = BN * 32;        // ushorts per B section
  constexpr int BUFU = 2 * ASEC + 2 * BSEC;  // ushorts per buffer
  constexpr int NJ = BN / 32;          // n-fragments per wave
  __shared__ ushort sm[2 * BUFU];      // BN=128: 64KB, BN=64: 48KB
  const int t = threadIdx.x;
  const int m0 = blockIdx.x * 128;
  const int n0 = blockIdx.y * BN;

  auto stage = [&](int c, int bufIdx) {
    ushort* secAh = sm + bufIdx * BUFU;
    ushort* secAl = secAh + ASEC;
    ushort* secBh = secAl + ASEC;
    ushort* secBl = secBh + BSEC;
    int off = 0, cc = 0, oy = 0, ox = 0;
    if (IM2COL) {
      off = c >> 5;   // 0..8  (ky*3+kx)
      cc = c & 31;    // ci chunk
      oy = off / 3;
      ox = off - 3 * oy;
    }
    // A: 512 slots, seg-major (row = L&127, seg = L>>7); wave = 1KB contig
#pragma unroll
    for (int q = 0; q < 2; ++q) {
      int L = t + 256 * q;
      int row = L & 127, seg = L >> 7;
      size_t aoff;
      if (IM2COL) {
        int m = m0 + row, y = m >> 6, xq = m & 63;
        aoff = ((size_t)(cc * 4 + seg) * 4356 + (y + oy) * 66 + (xq + ox)) * 16;
      } else {
        aoff = ((size_t)(c * 4 + seg) * 4096 + (m0 + row)) * 16;
      }
      gl_lds16((const char*)Ahi + aoff, (char*)secAh + L * 16);
      gl_lds16((const char*)Alo + aoff, (char*)secAl + L * 16);
    }
    // B: BN*4 slots, seg-major (row = L%BN, seg = L/BN); wave = 1KB contig
#pragma unroll
    for (int q = 0; q < BN / 64; ++q) {
      int L = t + 256 * q;
      int row = L % BN, seg = L / BN;
      size_t boff;
      if (IM2COL) {
        boff = (((size_t)(off * 32 + cc) * 4 + seg) * 1024 + (n0 + row)) * 16;
      } else {
        boff = ((size_t)(c * 4 + seg) * 128 + (n0 + row)) * 16;
      }
      gl_lds16((const char*)Bhi + boff, (char*)secBh + L * 16);
      gl_lds16((const char*)Blo + boff, (char*)secBl + L * 16);
    }
  };

  const int lane = t & 63, wv = t >> 6;
  const int wm = (wv & 1) * 64, wn = (wv >> 1) * (BN / 2);
  const int rA = wm + (lane & 15);
  const int rB = wn + (lane & 15);
  const int segA = (lane >> 4) * 2048;      // A seg region base (bytes)
  const int segB = (lane >> 4) * (BN * 16); // B seg region base (bytes)

  floatx4 acc[4][NJ];
#pragma unroll
  for (int i = 0; i < 4; ++i)
#pragma unroll
    for (int j = 0; j < NJ; ++j) acc[i][j] = (floatx4){0.f, 0.f, 0.f, 0.f};

  stage(0, 0);
  for (int kc = 0; kc < nChunks; ++kc) {
    __syncthreads();  // staged chunk kc landed; prev compute done
    if (kc + 1 < nChunks) stage(kc + 1, (kc + 1) & 1);  // overlap with compute
    const ushort* sb = sm + (kc & 1) * BUFU;
    const char* cAh = (const char*)sb;
    const char* cAl = (const char*)(sb + ASEC);
    const char* cBh = (const char*)(sb + 2 * ASEC);
    const char* cBl = (const char*)(sb + 2 * ASEC + BSEC);
    short8 ah[4], al[4], bh2[NJ], bl2[NJ];
#pragma unroll
    for (int i = 0; i < 4; ++i) {
      int pa = segA + (rA + 16 * i) * 16;
      ah[i] = *(const short8*)(cAh + pa);
      al[i] = *(const short8*)(cAl + pa);
    }
#pragma unroll
    for (int j = 0; j < NJ; ++j) {
      int pb = segB + (rB + 16 * j) * 16;
      bh2[j] = *(const short8*)(cBh + pb);
      bl2[j] = *(const short8*)(cBl + pb);
    }
#pragma unroll
    for (int i = 0; i < 4; ++i)
#pragma unroll
      for (int j = 0; j < NJ; ++j) {
        acc[i][j] = __builtin_amdgcn_mfma_f32_16x16x32_bf16(ah[i], bh2[j], acc[i][j], 0, 0, 0);
        acc[i][j] = __builtin_amdgcn_mfma_f32_16x16x32_bf16(ah[i], bl2[j], acc[i][j], 0, 0, 0);
        acc[i][j] = __builtin_amdgcn_mfma_f32_16x16x32_bf16(al[i], bh2[j], acc[i][j], 0, 0, 0);
      }
  }

#pragma unroll
  for (int i = 0; i < 4; ++i)
#pragma unroll
    for (int j = 0; j < NJ; ++j) {
      int nn = n0 + wn + 16 * j + (lane & 15);
      float bv = bias[nn];
#pragma unroll
      for (int r = 0; r < 4; ++r) {
        int mm = m0 + wm + 16 * i + (lane >> 4) * 4 + r;  // C: row=(lane>>4)*4+reg
        float v = acc[i][j][r] + bv;
        if (IM2COL) {
          v = fmaxf(v, 0.f);
          ushort h2 = bf16rne(v);
          float hf = __uint_as_float((uint)h2 << 16);
          ushort l2 = bf16rne(v - hf);
          int cc = nn >> 5, sg = (nn >> 3) & 3, e = nn & 7;
          size_t ho = ((size_t)(cc * 4 + sg) * 4096 + mm) * 8 + e;  // h layout
          outHi[ho] = h2;
          outLo[ho] = l2;
        } else {
          outRaw[(size_t)mm * 128 + nn] = v;
        }
      }
    }
}

// ---------------- decode + key + histogram ----------------------------------
__global__ __launch_bounds__(256) void decode_k(const float* __restrict__ raw,
                                                float* __restrict__ scores,
                                                float4* __restrict__ boxes,
                                                uint* __restrict__ key32,
                                                uint* __restrict__ hist) {
  int i = blockIdx.x * 256 + threadIdx.x;  // exactly 61440
  int m = i / 15, a = i - m * 15;
  int y = m >> 6, x = m & 63;
  const float* rp = raw + (size_t)m * 128;
  float logit = rp[a];
  float dx = rp[15 + 4 * a], dy = rp[16 + 4 * a];
  float dw = rp[17 + 4 * a], dh = rp[18 + 4 * a];
  int rr = a / 5, ss = a - rr * 5;
  float sc5 = (float)(2 << ss);
  float W = ((rr == 0) ? 23.f : (rr == 1) ? 16.f : 11.f) * sc5;
  float H = ((rr == 0) ? 12.f : (rr == 1) ? 16.f : 22.f) * sc5;
  float aw = W - 1.f, ah = H - 1.f;
  float ax = x * 16.f + 7.5f, ay = y * 16.f + 7.5f;
  float ox = dx * aw + ax, oyc = dy * ah + ay;
  float ow = expf(fminf(dw, 4.14f)) * aw * 0.5f;
  float oh = expf(fminf(dh, 4.14f)) * ah * 0.5f;
  float x1 = fminf(fmaxf(ox - ow, 0.f), 1023.f);
  float y1 = fminf(fmaxf(oyc - oh, 0.f), 1023.f);
  float x2 = fminf(fmaxf(ox + ow, 0.f), 1023.f);
  float y2 = fminf(fmaxf(oyc + oh, 0.f), 1023.f);
  bool inval = ((x2 - x1) < 16.f) || ((y2 - y1) < 16.f);
  float sc = inval ? -1.f : (1.f / (1.f + expf(-logit)));
  scores[i] = sc;
  boxes[i] = inval ? make_float4(-1.f, -1.f, -1.f, -1.f) : make_float4(x1, y1, x2, y2);
  uint kb = __float_as_uint(sc);
  uint key = (kb & 0x80000000u) ? ~kb : (kb | 0x80000000u);
  key32[i] = key;
  atomicAdd(&hist[key >> 16], 1u);
}

// ---------------- seg_sum: coalesced 256-entry segment sums of hist ---------
__global__ __launch_bounds__(256) void seg_sum(const uint* __restrict__ hist,
                                               uint* __restrict__ segsum) {
  __shared__ uint red[256];
  int b = blockIdx.x, t = threadIdx.x;
  red[t] = hist[b * 256 + t];  // coalesced 1KB per block
  __syncthreads();
  for (int d = 128; d > 0; d >>= 1) {
    if (t < d) red[t] += red[t + d];
    __syncthreads();
  }
  if (t == 0) segsum[b] = red[0];
}

// ---------------- find 16-bit prefix threshold for top-6000 -----------------
// (round-7: consumes precomputed segsum; round-6 version burned ~25us doing
// 256 serial 1KB-stride loads per thread. Integer sums -> identical selT.)
__global__ __launch_bounds__(256) void find_t16(const uint* __restrict__ hist,
                                                const uint* __restrict__ segsum,
                                                uint* __restrict__ selT) {
  __shared__ uint ps[256];
  __shared__ int segS;
  int t = threadIdx.x;
  ps[t] = segsum[t];
  __syncthreads();
  for (int d = 1; d < 256; d <<= 1) {
    uint v = ps[t] + ((t + d < 256) ? ps[t + d] : 0u);
    __syncthreads();
    ps[t] = v;
    __syncthreads();
  }
  if (ps[t] >= 6000u && (t == 255 || ps[t + 1] < 6000u)) segS = t;
  __syncthreads();
  int sg = segS;
  uint base = (sg == 255) ? 0u : ps[sg + 1];
  uint h2 = hist[sg * 256 + t];  // coalesced 1KB
  __syncthreads();
  ps[t] = h2;
  __syncthreads();
  for (int d = 1; d < 256; d <<= 1) {
    uint v = ps[t] + ((t + d < 256) ? ps[t + d] : 0u);
    __syncthreads();
    ps[t] = v;
    __syncthreads();
  }
  if (base + ps[t] >= 6000u && (t == 255 || base + ps[t + 1] < 6000u))
    *selT = (uint)(sg * 256 + t);
}

// ---------------- gather candidates (prefix >= T16) -------------------------
__global__ __launch_bounds__(256) void gather_k(const uint* __restrict__ key32,
                                                const uint* __restrict__ selT,
                                                uint* __restrict__ cnt,
                                                u64* __restrict__ cand) {
  int i = blockIdx.x * 256 + threadIdx.x;  // exactly 61440
  uint T = *selT;
  uint k = key32[i];
  if ((k >> 16) >= T) {
    uint pos = atomicAdd(cnt, 1u);
    if (pos < 8192) cand[pos] = ((u64)k << 32) | (u64)(~(uint)i);
  }
}

// ---------------- single-block bitonic sort (desc) + gather top-6000 --------
__global__ __launch_bounds__(1024) void sort_gather(
    const u64* __restrict__ cand, const uint* __restrict__ cnt,
    const float* __restrict__ scores, const float4* __restrict__ boxes,
    float* __restrict__ sortedS, float4* __restrict__ sortedB) {
  extern __shared__ u64 sk[];  // 8192 * 8 = 64 KB
  int t = threadIdx.x;
  int C = (int)*cnt;
  if (C > 8192) C = 8192;
  for (int j = t; j < 8192; j += 1024) sk[j] = (j < C) ? cand[j] : 0ull;
  __syncthreads();
  for (int k = 2; k <= 8192; k <<= 1) {
    for (int j2 = k >> 1; j2 > 0; j2 >>= 1) {
      for (int p = t; p < 4096; p += 1024) {
        int i = ((p & ~(j2 - 1)) << 1) | (p & (j2 - 1));
        int ix = i | j2;
        u64 a = sk[i], b = sk[ix];
        bool ddir = (i & k) != 0;
        if ((a < b) != ddir) { sk[i] = b; sk[ix] = a; }
      }
      __syncthreads();
    }
  }
  for (int j = t; j < 6016; j += 1024) {
    if (j < 6000) {
      u64 key = sk[j];
      uint idx = ~(uint)(key & 0xffffffffu);
      sortedS[j] = scores[idx];
      sortedB[j] = boxes[idx];
    } else {
      sortedS[j] = -1.f;
      sortedB[j] = make_float4(0.f, 0.f, 0.f, 0.f);
    }
  }
}

// ---------------- IoU suppression bitmask: mask[row][128 u64 words] ---------
__global__ __launch_bounds__(64) void iou_mask(const float4* __restrict__ boxes,
                                               u64* __restrict__ mask) {
  __shared__ float cx1[64], cy1[64], cx2[64], cy2[64], car[64];
  int bi = blockIdx.x, bj = blockIdx.y, t = threadIdx.x;
  float4 cb = boxes[bj * 64 + t];
  cx1[t] = cb.x; cy1[t] = cb.y; cx2[t] = cb.z; cy2[t] = cb.w;
  car[t] = (cb.z - cb.x) * (cb.w - cb.y);
  __syncthreads();
  int r = bi * 64 + t;
  float4 rb = boxes[r];
  float ra = (rb.z - rb.x) * (rb.w - rb.y);
  u64 wd = 0;
#pragma unroll 8
  for (int j = 0; j < 64; ++j) {
    float iw = fmaxf(fminf(rb.z, cx2[j]) - fmaxf(rb.x, cx1[j]), 0.f);
    float ih = fmaxf(fminf(rb.w, cy2[j]) - fmaxf(rb.y, cy1[j]), 0.f);
    float inter = iw * ih;
    float iou = inter / (ra + car[j] - inter + 1e-12f);
    if (iou > 0.7f && r != bj * 64 + j) wd |= (1ull << j);
  }
  mask[(size_t)r * 128 + bj] = wd;
}

// ---------------- serial NMS scan (1 wave), 2-slot pipelined row loads ------
// The pick loop is a serial dependent chain of ~1KB mask-row loads (~600-900cy
// each from remote-XCD L2/L3). Pipeline: while row i is in flight, issue a
// SPECULATIVE load for the next candidate (from pre-update rem). On hit the
// next pick's row is already in flight (~latency/2 per pick); on miss reissue.
// Picks are bit-identical (mask is constant; only load timing changes).
__global__ __launch_bounds__(64) void nms_scan(const u64* __restrict__ mask,
                                               const float* __restrict__ sortedS,
                                               const float4* __restrict__ sortedB,
                                               float* __restrict__ out) {
  __shared__ int klist[300];
  int lane = threadIdx.x;
  u64 Sx = 0, Sy = 0;  // lane l owns suppression words 2l and 2l+1
  for (int w2 = 0; w2 < 94; ++w2) {
    bool neg = sortedS[w2 * 64 + lane] < 0.f;
    u64 m2 = __ballot(neg);
    if ((w2 >> 1) == lane) { if (w2 & 1) Sy = m2; else Sx = m2; }
  }
  int count = 0;
  for (int w2 = 0; w2 < 94; ++w2) {
    u64 cur = __shfl((w2 & 1) ? Sy : Sx, w2 >> 1);
    u64 rem = ~cur;
    if (w2 == 93) rem &= (1ull << 48) - 1;  // rows 6000..6015 are pad
    if (!rem) continue;
    int bA = __builtin_ctzll(rem);
    ulonglong2 vA = ((const ulonglong2*)(mask + (size_t)(w2 * 64 + bA) * 128))[lane];
    int bB;
    ulonglong2 vB;
    for (;;) {
      {  // --- slot A current, speculate into slot B ---
        u64 remS = (bA == 63) ? 0ull : (rem & (~0ull << (bA + 1)));
        bB = remS ? __builtin_ctzll(remS) : -1;
        if (bB >= 0)
          vB = ((const ulonglong2*)(mask + (size_t)(w2 * 64 + bB) * 128))[lane];
        if (lane == 0) klist[count] = w2 * 64 + bA;
        count++;
        if (count == 300) goto done;
        Sx |= vA.x;
        Sy |= vA.y;
        u64 cur2 = __shfl((w2 & 1) ? Sy : Sx, w2 >> 1);
        rem = remS & ~cur2;
        if (!rem) break;
        int bn = __builtin_ctzll(rem);
        if (bn != bB) {  // misspeculation: reissue
          bB = bn;
          vB = ((const ulonglong2*)(mask + (size_t)(w2 * 64 + bB) * 128))[lane];
        }
      }
      {  // --- slot B current, speculate into slot A ---
        u64 remS = (bB == 63) ? 0ull : (rem & (~0ull << (bB + 1)));
        bA = remS ? __builtin_ctzll(remS) : -1;
        if (bA >= 0)
          vA = ((const ulonglong2*)(mask + (size_t)(w2 * 64 + bA) * 128))[lane];
        if (lane == 0) klist[count] = w2 * 64 + bB;
        count++;
        if (count == 300) goto done;
        Sx |= vB.x;
        Sy |= vB.y;
        u64 cur2 = __shfl((w2 & 1) ? Sy : Sx, w2 >> 1);
        rem = remS & ~cur2;
        if (!rem) break;
        int bn = __builtin_ctzll(rem);
        if (bn != bA) {  // misspeculation: reissue
          bA = bn;
          vA = ((const ulonglong2*)(mask + (size_t)(w2 * 64 + bA) * 128))[lane];
        }
      }
    }
  }
done:
  __syncthreads();
  for (int j = lane; j < 300; j += 64) {
    float s;
    float4 bb;
    if (j < count) {
      int i = klist[j];
      s = sortedS[i];
      bb = sortedB[i];
    } else {
      s = -1.f;
      bb = make_float4(-1.f, -1.f, -1.f, -1.f);
    }
    out[j * 5 + 0] = s;
    out[j * 5 + 1] = bb.x;
    out[j * 5 + 2] = bb.y;
    out[j * 5 + 3] = bb.z;
    out[j * 5 + 4] = bb.w;
  }
}

// ---------------- workspace layout (bytes) ----------------------------------
constexpr size_t O_XH = 0;                // 8,921,088   xpadT hi
constexpr size_t O_XL = 8921088;          // 8,921,088   xpadT lo
constexpr size_t O_WTH = 17842176;        // 18,874,368  wT hi
constexpr size_t O_WTL = 36716544;        // 18,874,368  wT lo
constexpr size_t O_HH = 55590912;         // 8,388,608   h hi
constexpr size_t O_HL = 63979520;         // 8,388,608   h lo
constexpr size_t O_WHH = 72368128;        // 262,144     head w hi
constexpr size_t O_WHL = 72630272;        // 262,144     head w lo
constexpr size_t O_BHD = 72892416;        // 512         head bias
constexpr size_t O_SC = 72892928;         // 245,760     scores
constexpr size_t O_BX = 73138688;         // 983,040     boxes (float4)
constexpr size_t O_KEY = 74121728;        // 245,760     key32
constexpr size_t O_HIST = 74367488;       // 262,144     histogram
constexpr size_t O_CNT = 74629632;        // 256         atomic counter
constexpr size_t O_CAND = 74629888;       // 65,536      candidates
constexpr size_t O_SELT = 74695424;       // 256         T16
constexpr size_t O_SS = 74695680;         // 24,064      sorted scores [6016]
constexpr size_t O_SB = 74719744;         // 96,256      sorted boxes  [6016]
// aliases (regions dead by the time these are written):
constexpr size_t O_RAW = 0;               // 2,097,152  raw head out (aliases xpadT, dead after conv GEMM)
constexpr size_t O_MASK = 17842176;       // 6,160,384  NMS mask (aliases wT, dead after conv GEMM)
constexpr size_t O_SEG = 24002560;        // 1,024      segsum (aliases wT tail; dead until iou_mask, unused by it)
// total distinct footprint ~74.8 MB

extern "C" void kernel_launch(void* const* d_in, const int* in_sizes, int n_in,
                              void* d_out, int out_size, void* d_ws,
                              size_t ws_size, hipStream_t stream) {
  (void)in_sizes; (void)n_in; (void)out_size; (void)ws_size;
  const float* x = (const float*)d_in[1];
  const float* conv_w = (const float*)d_in[2];
  const float* conv_b = (const float*)d_in[3];
  const float* score_w = (const float*)d_in[4];
  const float* score_b = (const float*)d_in[5];
  const float* loc_w = (const float*)d_in[6];
  const float* loc_b = (const float*)d_in[7];
  float* out = (float*)d_out;
  char* ws = (char*)d_ws;

  ushort* xh = (ushort*)(ws + O_XH);
  ushort* xl = (ushort*)(ws + O_XL);
  ushort* wTh = (ushort*)(ws + O_WTH);
  ushort* wTl = (ushort*)(ws + O_WTL);
  ushort* hh = (ushort*)(ws + O_HH);
  ushort* hl = (ushort*)(ws + O_HL);
  ushort* wHh = (ushort*)(ws + O_WHH);
  ushort* wHl = (ushort*)(ws + O_WHL);
  float* biasH = (float*)(ws + O_BHD);
  float* raw = (float*)(ws + O_RAW);
  float* scores = (float*)(ws + O_SC);
  float4* boxes = (float4*)(ws + O_BX);
  uint* key32 = (uint*)(ws + O_KEY);
  uint* hist = (uint*)(ws + O_HIST);
  uint* cnt = (uint*)(ws + O_CNT);
  u64* cand = (u64*)(ws + O_CAND);
  uint* selT = (uint*)(ws + O_SELT);
  float* sortedS = (float*)(ws + O_SS);
  float4* sortedB = (float4*)(ws + O_SB);
  u64* mask = (u64*)(ws + O_MASK);
  uint* segsum = (uint*)(ws + O_SEG);

  // zero the padded-input borders (whole buffer) and histogram+counter
  hipMemsetAsync(ws + O_XH, 0, 2 * 8921088, stream);
  hipMemsetAsync(ws + O_HIST, 0, 262144 + 256, stream);

  prep_x<<<dim3(16, 64), 256, 0, stream>>>(x, xh, xl);
  prep_w<<<dim3(1024, 4), 256, 0, stream>>>(conv_w, wTh, wTl);
  prep_head<<<512, 256, 0, stream>>>(score_w, loc_w, score_b, loc_b, wHh, wHl, biasH);

  // conv: M=4096, N=1024, K=9*1024 -> h (relu, bf16 hi/lo); tile 128x64,
  // grid (32,16)=512 blocks -> 2 blocks/CU; K order bit-identical to round 0
  gemm_bf16x3<1, 64><<<dim3(32, 16), 256, 0, stream>>>(xh, xl, wTh, wTl, conv_b,
                                                       288, nullptr, hh, hl);
  // heads: M=4096, N=128(pad), K=1024 -> raw f32 (tile 128x128)
  gemm_bf16x3<0, 128><<<dim3(32, 1), 256, 0, stream>>>(hh, hl, wHh, wHl, biasH,
                                                       32, raw, nullptr, nullptr);

  decode_k<<<240, 256, 0, stream>>>(raw, scores, boxes, key32, hist);
  seg_sum<<<256, 256, 0, stream>>>(hist, segsum);
  find_t16<<<1, 256, 0, stream>>>(hist, segsum, selT);
  gather_k<<<240, 256, 0, stream>>>(key32, selT, cnt, cand);
  sort_gather<<<1, 1024, 65536, stream>>>(cand, cnt, scores, boxes, sortedS, sortedB);
  iou_mask<<<dim3(94, 94), 64, 0, stream>>>(sortedB, mask);
  nms_scan<<<1, 64, 0, stream>>>(mask, sortedS, sortedB, out);
}

// Round 8
// 715.332 us; speedup vs baseline: 1.3251x; 1.0106x over previous
//
#include <hip/hip_runtime.h>

typedef unsigned int uint;
typedef unsigned short ushort;
typedef unsigned long long u64;

typedef __attribute__((ext_vector_type(8))) short short8;
typedef __attribute__((ext_vector_type(4))) float floatx4;

// ---------------- helpers ----------------
__device__ inline ushort bf16rne(float v) {
  uint b = __float_as_uint(v);
  uint r = (b + 0x7fffu + ((b >> 16) & 1u)) >> 16;
  return (ushort)r;
}

__device__ inline void gl_lds16(const void* g, void* l) {
  __builtin_amdgcn_global_load_lds(
      (const __attribute__((address_space(1))) unsigned int*)g,
      (__attribute__((address_space(3))) unsigned int*)l, 16, 0, 0);
}

// ======================= chunk-seg-major global layouts =====================
//   xpadT: [cc 32][seg 4][spatial 66*66][8e]   (ci = cc*32 + seg*8 + e)
//   wT:    [off*32+cc][seg 4][co 1024][8e]
//   h:     [cc 32][seg 4][m 4096][8e]
//   wH:    [cc 32][seg 4][o 128][8e]
// Proven round 6: seg-major LDS stage = 0 bank conflicts AND coalesced wave
// staging (conv 484 -> 209us). Round 8: preps re-blocked by (cc,sg) so their
// WRITES are also contiguous (round 6 made them 2-16B scatters, +60us).

// ---------------- prep: x -> padded transposed bf16 hi/lo -------------------
// block = (cc, sg, spatial-half); reads 8 ci-planes coalesced, LDS transpose,
// writes contiguous short8 per spatial cell. Border cells stay memset-zero.
__global__ __launch_bounds__(256) void prep_x(const float* __restrict__ x,
                                              ushort* __restrict__ xh,
                                              ushort* __restrict__ xl) {
  __shared__ float tile[8][512];
  int cc = blockIdx.x, sg = blockIdx.y, t = threadIdx.x;
  int ci0 = cc * 32 + sg * 8;
  size_t obase = (size_t)(cc * 4 + sg) * 4356;
  for (int it = 0; it < 4; ++it) {
    int s0 = blockIdx.z * 2048 + it * 512;
#pragma unroll
    for (int e = 0; e < 8; ++e) {
      tile[e][t] = x[(size_t)(ci0 + e) * 4096 + s0 + t];
      tile[e][t + 256] = x[(size_t)(ci0 + e) * 4096 + s0 + 256 + t];
    }
    __syncthreads();
#pragma unroll
    for (int w = 0; w < 2; ++w) {
      int sl = w * 256 + t;
      int s = s0 + sl;
      int y = s >> 6, xx = s & 63;
      short8 sh, slo;
#pragma unroll
      for (int e = 0; e < 8; ++e) {
        float v = tile[e][sl];
        ushort h2 = bf16rne(v);
        float hf = __uint_as_float((uint)h2 << 16);
        sh[e] = (short)h2;
        slo[e] = (short)bf16rne(v - hf);
      }
      size_t o = (obase + (size_t)(y + 1) * 66 + (xx + 1)) * 8;
      *(short8*)(xh + o) = sh;
      *(short8*)(xl + o) = slo;
    }
    __syncthreads();
  }
}

// ---------------- prep: conv_w[co][ci][3][3] -> wT chunk-seg-major ----------
// block = (cc, sg, co-quarter); thread = (col, e): reads its 9 contiguous
// floats once, writes 9 offs as fully-coalesced 2B runs (consecutive t ->
// consecutive co*8+e).
__global__ __launch_bounds__(256) void prep_w(const float* __restrict__ w,
                                              ushort* __restrict__ wh,
                                              ushort* __restrict__ wl) {
  int cc = blockIdx.x, sg = blockIdx.y, t = threadIdx.x;
  int e = t & 7, col = t >> 3;
  int ci = cc * 32 + sg * 8 + e;
  for (int chunk = 0; chunk < 8; ++chunk) {
    int co = blockIdx.z * 256 + chunk * 32 + col;
    const float* src = w + ((size_t)co * 1024 + ci) * 9;
    float v[9];
#pragma unroll
    for (int o = 0; o < 9; ++o) v[o] = src[o];
#pragma unroll
    for (int off = 0; off < 9; ++off) {
      ushort h2 = bf16rne(v[off]);
      float hf = __uint_as_float((uint)h2 << 16);
      ushort l2 = bf16rne(v[off] - hf);
      size_t oi = ((size_t)(off * 32 + cc) * 4 + sg) * 8192 + (size_t)co * 8 + e;
      wh[oi] = h2;
      wl[oi] = l2;
    }
  }
}

// ---------------- prep: head weights -> wH chunk-seg-major + bias[128] ------
__global__ __launch_bounds__(256) void prep_head(
    const float* __restrict__ score_w, const float* __restrict__ loc_w,
    const float* __restrict__ score_b, const float* __restrict__ loc_b,
    ushort* __restrict__ wh, ushort* __restrict__ wl, float* __restrict__ bh) {
  int idx = blockIdx.x * 256 + threadIdx.x;  // < 131072
  int o = idx >> 10, ci = idx & 1023;
  float v = 0.f;
  if (o < 15) v = score_w[o * 1024 + ci];
  else if (o < 75) v = loc_w[(o - 15) * 1024 + ci];
  ushort h2 = bf16rne(v);
  float hf = __uint_as_float((uint)h2 << 16);
  int cc = ci >> 5, sg = (ci >> 3) & 3, e = ci & 7;
  size_t oi = ((size_t)(cc * 4 + sg) * 128 + o) * 8 + e;
  wh[oi] = h2;
  wl[oi] = bf16rne(v - hf);
  if (idx < 128) bh[idx] = (idx < 15) ? score_b[idx] : ((idx < 75) ? loc_b[idx - 15] : 0.f);
}

// ---------------- bf16x3 GEMM: C[m][n] = sum_k A[m][k]*B[n][k] --------------
// Tile BM x BN, 256 threads (4 waves). K-accumulation order BIT-IDENTICAL to
// round 0 per output element (sequential chunks, hh/hl/lh MFMA order).
// Round 8: B operands live in REGISTERS (double-buffered one chunk ahead,
// explicit even/odd unroll -- no runtime-indexed reg arrays), loaded straight
// from chunk-seg-major wT (L2-hot: shared across all x-blocks). Removes B's
// LDS stage-write + frag-read: 72 -> 48 KB LDS per chunk per block -- the
// conv was LDS-throughput-bound at 209us (MfmaUtil 52%, conflicts 0).
// A stays LDS-staged (seg-major [4 segs][BM rows][16B], linear gl_lds dest).
// Conv: BM=128,BN=64, grid (32,16) = 2 blocks/CU. Head: BM=32,BN=128,
// grid (128,1) (was 32 blocks = 87% CUs idle).
template <int IM2COL, int BM, int BN>
__global__ __launch_bounds__(256, 1) void gemm_bf16x3(
    const ushort* __restrict__ Ahi, const ushort* __restrict__ Alo,
    const ushort* __restrict__ Bhi, const ushort* __restrict__ Blo,
    const float* __restrict__ bias, int nChunks, float* __restrict__ outRaw,
    ushort* __restrict__ outHi, ushort* __restrict__ outLo) {
  constexpr int ASEC = BM * 32;        // ushorts per A section
  constexpr int BUFU = 2 * ASEC;       // ushorts per buffer {Ah, Al}
  constexpr int WM = (BM >= 128) ? 2 : 1;  // wave grid
  constexpr int WN = 4 / WM;
  constexpr int MI = (BM / WM) / 16;   // m-fragments per wave
  constexpr int NJ = (BN / WN) / 16;   // n-fragments per wave
  __shared__ ushort sm[2 * BUFU];      // conv: 32KB, head: 8KB
  const int t = threadIdx.x;
  const int m0 = blockIdx.x * BM;
  const int n0 = blockIdx.y * BN;

  const int lane = t & 63, wv = t >> 6;
  const int wm = (wv % WM) * (BM / WM);
  const int wn = (wv / WM) * (BN / WN);
  const int rA = wm + (lane & 15);
  const int segA = (lane >> 4) * (BM * 16);  // A seg region base (bytes)

  auto stage = [&](int c, int bufIdx) {
    ushort* secAh = sm + bufIdx * BUFU;
    ushort* secAl = secAh + ASEC;
    int cc = 0, oy = 0, ox = 0;
    if (IM2COL) {
      int off = c >> 5;  // 0..8  (ky*3+kx)
      cc = c & 31;       // ci chunk
      oy = off / 3;
      ox = off - 3 * oy;
    }
    // A: BM*4 slots, seg-major (row = L%BM, seg = L/BM); wave = 1KB contig
    for (int L = t; L < BM * 4; L += 256) {
      int row = L % BM, seg = L / BM;
      size_t aoff;
      if (IM2COL) {
        int m = m0 + row, y = m >> 6, xq = m & 63;
        aoff = ((size_t)(cc * 4 + seg) * 4356 + (y + oy) * 66 + (xq + ox)) * 16;
      } else {
        aoff = ((size_t)(c * 4 + seg) * 4096 + (m0 + row)) * 16;
      }
      gl_lds16((const char*)Ahi + aoff, (char*)secAh + L * 16);
      gl_lds16((const char*)Alo + aoff, (char*)secAl + L * 16);
    }
  };

  auto loadB = [&](int c, short8* bh, short8* bl) {
    int sg = lane >> 4;
#pragma unroll
    for (int j = 0; j < NJ; ++j) {
      int co = n0 + wn + (lane & 15) + 16 * j;
      size_t boff;
      if (IM2COL) {
        int off = c >> 5, cc = c & 31;
        boff = (((size_t)(off * 32 + cc) * 4 + sg) * 1024 + co) * 16;
      } else {
        boff = (((size_t)(c * 4 + sg)) * 128 + co) * 16;
      }
      bh[j] = *(const short8*)((const char*)Bhi + boff);
      bl[j] = *(const short8*)((const char*)Blo + boff);
    }
  };

  floatx4 acc[MI][NJ];
#pragma unroll
  for (int i = 0; i < MI; ++i)
#pragma unroll
    for (int j = 0; j < NJ; ++j) acc[i][j] = (floatx4){0.f, 0.f, 0.f, 0.f};

  auto compute = [&](const ushort* sb, const short8* bh2, const short8* bl2) {
    const char* cAh = (const char*)sb;
    const char* cAl = (const char*)(sb + ASEC);
    short8 ah[MI], al[MI];
#pragma unroll
    for (int i = 0; i < MI; ++i) {
      int pa = segA + (rA + 16 * i) * 16;
      ah[i] = *(const short8*)(cAh + pa);
      al[i] = *(const short8*)(cAl + pa);
    }
#pragma unroll
    for (int i = 0; i < MI; ++i)
#pragma unroll
      for (int j = 0; j < NJ; ++j) {
        acc[i][j] = __builtin_amdgcn_mfma_f32_16x16x32_bf16(ah[i], bh2[j], acc[i][j], 0, 0, 0);
        acc[i][j] = __builtin_amdgcn_mfma_f32_16x16x32_bf16(ah[i], bl2[j], acc[i][j], 0, 0, 0);
        acc[i][j] = __builtin_amdgcn_mfma_f32_16x16x32_bf16(al[i], bh2[j], acc[i][j], 0, 0, 0);
      }
  };

  short8 b0h[NJ], b0l[NJ], b1h[NJ], b1l[NJ];
  stage(0, 0);
  loadB(0, b0h, b0l);
  for (int kc = 0; kc < nChunks; kc += 2) {  // nChunks even (288 / 32)
    __syncthreads();  // A chunk kc staged; buf1 reads of kc-1 done
    if (kc + 1 < nChunks) { stage(kc + 1, 1); loadB(kc + 1, b1h, b1l); }
    compute(sm, b0h, b0l);
    __syncthreads();  // A chunk kc+1 staged; buf0 reads of kc done
    if (kc + 2 < nChunks) { stage(kc + 2, 0); loadB(kc + 2, b0h, b0l); }
    compute(sm + BUFU, b1h, b1l);
  }

#pragma unroll
  for (int i = 0; i < MI; ++i)
#pragma unroll
    for (int j = 0; j < NJ; ++j) {
      int nn = n0 + wn + 16 * j + (lane & 15);
      float bv = bias[nn];
#pragma unroll
      for (int r = 0; r < 4; ++r) {
        int mm = m0 + wm + 16 * i + (lane >> 4) * 4 + r;  // C: row=(lane>>4)*4+reg
        float v = acc[i][j][r] + bv;
        if (IM2COL) {
          v = fmaxf(v, 0.f);
          ushort h2 = bf16rne(v);
          float hf = __uint_as_float((uint)h2 << 16);
          ushort l2 = bf16rne(v - hf);
          int cc = nn >> 5, sg = (nn >> 3) & 3, e = nn & 7;
          size_t ho = ((size_t)(cc * 4 + sg) * 4096 + mm) * 8 + e;  // h layout
          outHi[ho] = h2;
          outLo[ho] = l2;
        } else {
          outRaw[(size_t)mm * 128 + nn] = v;
        }
      }
    }
}

// ---------------- decode + key + histogram ----------------------------------
__global__ __launch_bounds__(256) void decode_k(const float* __restrict__ raw,
                                                float* __restrict__ scores,
                                                float4* __restrict__ boxes,
                                                uint* __restrict__ key32,
                                                uint* __restrict__ hist) {
  int i = blockIdx.x * 256 + threadIdx.x;  // exactly 61440
  int m = i / 15, a = i - m * 15;
  int y = m >> 6, x = m & 63;
  const float* rp = raw + (size_t)m * 128;
  float logit = rp[a];
  float dx = rp[15 + 4 * a], dy = rp[16 + 4 * a];
  float dw = rp[17 + 4 * a], dh = rp[18 + 4 * a];
  int rr = a / 5, ss = a - rr * 5;
  float sc5 = (float)(2 << ss);
  float W = ((rr == 0) ? 23.f : (rr == 1) ? 16.f : 11.f) * sc5;
  float H = ((rr == 0) ? 12.f : (rr == 1) ? 16.f : 22.f) * sc5;
  float aw = W - 1.f, ah = H - 1.f;
  float ax = x * 16.f + 7.5f, ay = y * 16.f + 7.5f;
  float ox = dx * aw + ax, oyc = dy * ah + ay;
  float ow = expf(fminf(dw, 4.14f)) * aw * 0.5f;
  float oh = expf(fminf(dh, 4.14f)) * ah * 0.5f;
  float x1 = fminf(fmaxf(ox - ow, 0.f), 1023.f);
  float y1 = fminf(fmaxf(oyc - oh, 0.f), 1023.f);
  float x2 = fminf(fmaxf(ox + ow, 0.f), 1023.f);
  float y2 = fminf(fmaxf(oyc + oh, 0.f), 1023.f);
  bool inval = ((x2 - x1) < 16.f) || ((y2 - y1) < 16.f);
  float sc = inval ? -1.f : (1.f / (1.f + expf(-logit)));
  scores[i] = sc;
  boxes[i] = inval ? make_float4(-1.f, -1.f, -1.f, -1.f) : make_float4(x1, y1, x2, y2);
  uint kb = __float_as_uint(sc);
  uint key = (kb & 0x80000000u) ? ~kb : (kb | 0x80000000u);
  key32[i] = key;
  atomicAdd(&hist[key >> 16], 1u);
}

// ---------------- seg_sum: coalesced 256-entry segment sums of hist ---------
__global__ __launch_bounds__(256) void seg_sum(const uint* __restrict__ hist,
                                               uint* __restrict__ segsum) {
  __shared__ uint red[256];
  int b = blockIdx.x, t = threadIdx.x;
  red[t] = hist[b * 256 + t];  // coalesced 1KB per block
  __syncthreads();
  for (int d = 128; d > 0; d >>= 1) {
    if (t < d) red[t] += red[t + d];
    __syncthreads();
  }
  if (t == 0) segsum[b] = red[0];
}

// ---------------- find 16-bit prefix threshold for top-6000 -----------------
__global__ __launch_bounds__(256) void find_t16(const uint* __restrict__ hist,
                                                const uint* __restrict__ segsum,
                                                uint* __restrict__ selT) {
  __shared__ uint ps[256];
  __shared__ int segS;
  int t = threadIdx.x;
  ps[t] = segsum[t];
  __syncthreads();
  for (int d = 1; d < 256; d <<= 1) {
    uint v = ps[t] + ((t + d < 256) ? ps[t + d] : 0u);
    __syncthreads();
    ps[t] = v;
    __syncthreads();
  }
  if (ps[t] >= 6000u && (t == 255 || ps[t + 1] < 6000u)) segS = t;
  __syncthreads();
  int sg = segS;
  uint base = (sg == 255) ? 0u : ps[sg + 1];
  uint h2 = hist[sg * 256 + t];  // coalesced 1KB
  __syncthreads();
  ps[t] = h2;
  __syncthreads();
  for (int d = 1; d < 256; d <<= 1) {
    uint v = ps[t] + ((t + d < 256) ? ps[t + d] : 0u);
    __syncthreads();
    ps[t] = v;
    __syncthreads();
  }
  if (base + ps[t] >= 6000u && (t == 255 || base + ps[t + 1] < 6000u))
    *selT = (uint)(sg * 256 + t);
}

// ---------------- gather candidates (prefix >= T16) -------------------------
__global__ __launch_bounds__(256) void gather_k(const uint* __restrict__ key32,
                                                const uint* __restrict__ selT,
                                                uint* __restrict__ cnt,
                                                u64* __restrict__ cand) {
  int i = blockIdx.x * 256 + threadIdx.x;  // exactly 61440
  uint T = *selT;
  uint k = key32[i];
  if ((k >> 16) >= T) {
    uint pos = atomicAdd(cnt, 1u);
    if (pos < 8192) cand[pos] = ((u64)k << 32) | (u64)(~(uint)i);
  }
}

// ---------------- single-block bitonic sort (desc) + gather top-6000 --------
__global__ __launch_bounds__(1024) void sort_gather(
    const u64* __restrict__ cand, const uint* __restrict__ cnt,
    const float* __restrict__ scores, const float4* __restrict__ boxes,
    float* __restrict__ sortedS, float4* __restrict__ sortedB) {
  extern __shared__ u64 sk[];  // 8192 * 8 = 64 KB
  int t = threadIdx.x;
  int C = (int)*cnt;
  if (C > 8192) C = 8192;
  for (int j = t; j < 8192; j += 1024) sk[j] = (j < C) ? cand[j] : 0ull;
  __syncthreads();
  for (int k = 2; k <= 8192; k <<= 1) {
    for (int j2 = k >> 1; j2 > 0; j2 >>= 1) {
      for (int p = t; p < 4096; p += 1024) {
        int i = ((p & ~(j2 - 1)) << 1) | (p & (j2 - 1));
        int ix = i | j2;
        u64 a = sk[i], b = sk[ix];
        bool ddir = (i & k) != 0;
        if ((a < b) != ddir) { sk[i] = b; sk[ix] = a; }
      }
      __syncthreads();
    }
  }
  for (int j = t; j < 6016; j += 1024) {
    if (j < 6000) {
      u64 key = sk[j];
      uint idx = ~(uint)(key & 0xffffffffu);
      sortedS[j] = scores[idx];
      sortedB[j] = boxes[idx];
    } else {
      sortedS[j] = -1.f;
      sortedB[j] = make_float4(0.f, 0.f, 0.f, 0.f);
    }
  }
}

// ---------------- IoU suppression bitmask: mask[row][128 u64 words] ---------
__global__ __launch_bounds__(64) void iou_mask(const float4* __restrict__ boxes,
                                               u64* __restrict__ mask) {
  __shared__ float cx1[64], cy1[64], cx2[64], cy2[64], car[64];
  int bi = blockIdx.x, bj = blockIdx.y, t = threadIdx.x;
  float4 cb = boxes[bj * 64 + t];
  cx1[t] = cb.x; cy1[t] = cb.y; cx2[t] = cb.z; cy2[t] = cb.w;
  car[t] = (cb.z - cb.x) * (cb.w - cb.y);
  __syncthreads();
  int r = bi * 64 + t;
  float4 rb = boxes[r];
  float ra = (rb.z - rb.x) * (rb.w - rb.y);
  u64 wd = 0;
#pragma unroll 8
  for (int j = 0; j < 64; ++j) {
    float iw = fmaxf(fminf(rb.z, cx2[j]) - fmaxf(rb.x, cx1[j]), 0.f);
    float ih = fmaxf(fminf(rb.w, cy2[j]) - fmaxf(rb.y, cy1[j]), 0.f);
    float inter = iw * ih;
    float iou = inter / (ra + car[j] - inter + 1e-12f);
    if (iou > 0.7f && r != bj * 64 + j) wd |= (1ull << j);
  }
  mask[(size_t)r * 128 + bj] = wd;
}

// ---------------- serial NMS scan (1 wave), 2-slot pipelined row loads ------
__global__ __launch_bounds__(64) void nms_scan(const u64* __restrict__ mask,
                                               const float* __restrict__ sortedS,
                                               const float4* __restrict__ sortedB,
                                               float* __restrict__ out) {
  __shared__ int klist[300];
  int lane = threadIdx.x;
  u64 Sx = 0, Sy = 0;  // lane l owns suppression words 2l and 2l+1
  for (int w2 = 0; w2 < 94; ++w2) {
    bool neg = sortedS[w2 * 64 + lane] < 0.f;
    u64 m2 = __ballot(neg);
    if ((w2 >> 1) == lane) { if (w2 & 1) Sy = m2; else Sx = m2; }
  }
  int count = 0;
  for (int w2 = 0; w2 < 94; ++w2) {
    u64 cur = __shfl((w2 & 1) ? Sy : Sx, w2 >> 1);
    u64 rem = ~cur;
    if (w2 == 93) rem &= (1ull << 48) - 1;  // rows 6000..6015 are pad
    if (!rem) continue;
    int bA = __builtin_ctzll(rem);
    ulonglong2 vA = ((const ulonglong2*)(mask + (size_t)(w2 * 64 + bA) * 128))[lane];
    int bB;
    ulonglong2 vB;
    for (;;) {
      {  // --- slot A current, speculate into slot B ---
        u64 remS = (bA == 63) ? 0ull : (rem & (~0ull << (bA + 1)));
        bB = remS ? __builtin_ctzll(remS) : -1;
        if (bB >= 0)
          vB = ((const ulonglong2*)(mask + (size_t)(w2 * 64 + bB) * 128))[lane];
        if (lane == 0) klist[count] = w2 * 64 + bA;
        count++;
        if (count == 300) goto done;
        Sx |= vA.x;
        Sy |= vA.y;
        u64 cur2 = __shfl((w2 & 1) ? Sy : Sx, w2 >> 1);
        rem = remS & ~cur2;
        if (!rem) break;
        int bn = __builtin_ctzll(rem);
        if (bn != bB) {  // misspeculation: reissue
          bB = bn;
          vB = ((const ulonglong2*)(mask + (size_t)(w2 * 64 + bB) * 128))[lane];
        }
      }
      {  // --- slot B current, speculate into slot A ---
        u64 remS = (bB == 63) ? 0ull : (rem & (~0ull << (bB + 1)));
        bA = remS ? __builtin_ctzll(remS) : -1;
        if (bA >= 0)
          vA = ((const ulonglong2*)(mask + (size_t)(w2 * 64 + bA) * 128))[lane];
        if (lane == 0) klist[count] = w2 * 64 + bB;
        count++;
        if (count == 300) goto done;
        Sx |= vB.x;
        Sy |= vB.y;
        u64 cur2 = __shfl((w2 & 1) ? Sy : Sx, w2 >> 1);
        rem = remS & ~cur2;
        if (!rem) break;
        int bn = __builtin_ctzll(rem);
        if (bn != bA) {  // misspeculation: reissue
          bA = bn;
          vA = ((const ulonglong2*)(mask + (size_t)(w2 * 64 + bA) * 128))[lane];
        }
      }
    }
  }
done:
  __syncthreads();
  for (int j = lane; j < 300; j += 64) {
    float s;
    float4 bb;
    if (j < count) {
      int i = klist[j];
      s = sortedS[i];
      bb = sortedB[i];
    } else {
      s = -1.f;
      bb = make_float4(-1.f, -1.f, -1.f, -1.f);
    }
    out[j * 5 + 0] = s;
    out[j * 5 + 1] = bb.x;
    out[j * 5 + 2] = bb.y;
    out[j * 5 + 3] = bb.z;
    out[j * 5 + 4] = bb.w;
  }
}

// ---------------- workspace layout (bytes) ----------------------------------
constexpr size_t O_XH = 0;                // 8,921,088   xpadT hi
constexpr size_t O_XL = 8921088;          // 8,921,088   xpadT lo
constexpr size_t O_WTH = 17842176;        // 18,874,368  wT hi
constexpr size_t O_WTL = 36716544;        // 18,874,368  wT lo
constexpr size_t O_HH = 55590912;         // 8,388,608   h hi
constexpr size_t O_HL = 63979520;         // 8,388,608   h lo
constexpr size_t O_WHH = 72368128;        // 262,144     head w hi
constexpr size_t O_WHL = 72630272;        // 262,144     head w lo
constexpr size_t O_BHD = 72892416;        // 512         head bias
constexpr size_t O_SC = 72892928;         // 245,760     scores
constexpr size_t O_BX = 73138688;         // 983,040     boxes (float4)
constexpr size_t O_KEY = 74121728;        // 245,760     key32
constexpr size_t O_HIST = 74367488;       // 262,144     histogram
constexpr size_t O_CNT = 74629632;        // 256         atomic counter
constexpr size_t O_CAND = 74629888;       // 65,536      candidates
constexpr size_t O_SELT = 74695424;       // 256         T16
constexpr size_t O_SS = 74695680;         // 24,064      sorted scores [6016]
constexpr size_t O_SB = 74719744;         // 96,256      sorted boxes  [6016]
// aliases (regions dead by the time these are written):
constexpr size_t O_RAW = 0;               // 2,097,152  raw head out (aliases xpadT, dead after conv GEMM)
constexpr size_t O_MASK = 17842176;       // 6,160,384  NMS mask (aliases wT, dead after conv GEMM)
constexpr size_t O_SEG = 24002560;        // 1,024      segsum (aliases wT tail)
// total distinct footprint ~74.8 MB

extern "C" void kernel_launch(void* const* d_in, const int* in_sizes, int n_in,
                              void* d_out, int out_size, void* d_ws,
                              size_t ws_size, hipStream_t stream) {
  (void)in_sizes; (void)n_in; (void)out_size; (void)ws_size;
  const float* x = (const float*)d_in[1];
  const float* conv_w = (const float*)d_in[2];
  const float* conv_b = (const float*)d_in[3];
  const float* score_w = (const float*)d_in[4];
  const float* score_b = (const float*)d_in[5];
  const float* loc_w = (const float*)d_in[6];
  const float* loc_b = (const float*)d_in[7];
  float* out = (float*)d_out;
  char* ws = (char*)d_ws;

  ushort* xh = (ushort*)(ws + O_XH);
  ushort* xl = (ushort*)(ws + O_XL);
  ushort* wTh = (ushort*)(ws + O_WTH);
  ushort* wTl = (ushort*)(ws + O_WTL);
  ushort* hh = (ushort*)(ws + O_HH);
  ushort* hl = (ushort*)(ws + O_HL);
  ushort* wHh = (ushort*)(ws + O_WHH);
  ushort* wHl = (ushort*)(ws + O_WHL);
  float* biasH = (float*)(ws + O_BHD);
  float* raw = (float*)(ws + O_RAW);
  float* scores = (float*)(ws + O_SC);
  float4* boxes = (float4*)(ws + O_BX);
  uint* key32 = (uint*)(ws + O_KEY);
  uint* hist = (uint*)(ws + O_HIST);
  uint* cnt = (uint*)(ws + O_CNT);
  u64* cand = (u64*)(ws + O_CAND);
  uint* selT = (uint*)(ws + O_SELT);
  float* sortedS = (float*)(ws + O_SS);
  float4* sortedB = (float4*)(ws + O_SB);
  u64* mask = (u64*)(ws + O_MASK);
  uint* segsum = (uint*)(ws + O_SEG);

  // zero the padded-input borders (whole buffer) and histogram+counter
  hipMemsetAsync(ws + O_XH, 0, 2 * 8921088, stream);
  hipMemsetAsync(ws + O_HIST, 0, 262144 + 256, stream);

  prep_x<<<dim3(32, 4, 2), 256, 0, stream>>>(x, xh, xl);
  prep_w<<<dim3(32, 4, 4), 256, 0, stream>>>(conv_w, wTh, wTl);
  prep_head<<<512, 256, 0, stream>>>(score_w, loc_w, score_b, loc_b, wHh, wHl, biasH);

  // conv: M=4096, N=1024, K=9*1024 -> h (relu, bf16 hi/lo); tile 128x64,
  // grid (32,16)=512 blocks -> 2 blocks/CU; B in regs, A in LDS
  gemm_bf16x3<1, 128, 64><<<dim3(32, 16), 256, 0, stream>>>(
      xh, xl, wTh, wTl, conv_b, 288, nullptr, hh, hl);
  // heads: M=4096, N=128(pad), K=1024 -> raw f32; tile 32x128, 128 blocks
  gemm_bf16x3<0, 32, 128><<<dim3(128, 1), 256, 0, stream>>>(
      hh, hl, wHh, wHl, biasH, 32, raw, nullptr, nullptr);

  decode_k<<<240, 256, 0, stream>>>(raw, scores, boxes, key32, hist);
  seg_sum<<<256, 256, 0, stream>>>(hist, segsum);
  find_t16<<<1, 256, 0, stream>>>(hist, segsum, selT);
  gather_k<<<240, 256, 0, stream>>>(key32, selT, cnt, cand);
  sort_gather<<<1, 1024, 65536, stream>>>(cand, cnt, scores, boxes, sortedS, sortedB);
  iou_mask<<<dim3(94, 94), 64, 0, stream>>>(sortedB, mask);
  nms_scan<<<1, 64, 0, stream>>>(mask, sortedS, sortedB, out);
}

// Round 9
// 705.548 us; speedup vs baseline: 1.3435x; 1.0139x over previous
//
#include <hip/hip_runtime.h>

typedef unsigned int uint;
typedef unsigned short ushort;
typedef unsigned long long u64;

typedef __attribute__((ext_vector_type(8))) short short8;
typedef __attribute__((ext_vector_type(4))) float floatx4;

// ---------------- helpers ----------------
__device__ inline ushort bf16rne(float v) {
  uint b = __float_as_uint(v);
  uint r = (b + 0x7fffu + ((b >> 16) & 1u)) >> 16;
  return (ushort)r;
}

__device__ inline void gl_lds16(const void* g, void* l) {
  __builtin_amdgcn_global_load_lds(
      (const __attribute__((address_space(1))) unsigned int*)g,
      (__attribute__((address_space(3))) unsigned int*)l, 16, 0, 0);
}

// ======================= chunk-seg-major global layouts =====================
//   xpadT: [cc 32][seg 4][spatial 66*66][8e]   (ci = cc*32 + seg*8 + e)
//   wT:    [off*32+cc][seg 4][co 1024][8e]
//   h:     [cc 32][seg 4][m 4096][8e]
//   wH:    [cc 32][seg 4][o 128][8e]
// Proven: seg-major LDS stage = 0 bank conflicts + coalesced wave staging.

// ---------------- prep: x -> padded transposed bf16 hi/lo -------------------
__global__ __launch_bounds__(256) void prep_x(const float* __restrict__ x,
                                              ushort* __restrict__ xh,
                                              ushort* __restrict__ xl) {
  __shared__ float tile[8][512];
  int cc = blockIdx.x, sg = blockIdx.y, t = threadIdx.x;
  int ci0 = cc * 32 + sg * 8;
  size_t obase = (size_t)(cc * 4 + sg) * 4356;
  for (int it = 0; it < 4; ++it) {
    int s0 = blockIdx.z * 2048 + it * 512;
#pragma unroll
    for (int e = 0; e < 8; ++e) {
      tile[e][t] = x[(size_t)(ci0 + e) * 4096 + s0 + t];
      tile[e][t + 256] = x[(size_t)(ci0 + e) * 4096 + s0 + 256 + t];
    }
    __syncthreads();
#pragma unroll
    for (int w = 0; w < 2; ++w) {
      int sl = w * 256 + t;
      int s = s0 + sl;
      int y = s >> 6, xx = s & 63;
      short8 sh, slo;
#pragma unroll
      for (int e = 0; e < 8; ++e) {
        float v = tile[e][sl];
        ushort h2 = bf16rne(v);
        float hf = __uint_as_float((uint)h2 << 16);
        sh[e] = (short)h2;
        slo[e] = (short)bf16rne(v - hf);
      }
      size_t o = (obase + (size_t)(y + 1) * 66 + (xx + 1)) * 8;
      *(short8*)(xh + o) = sh;
      *(short8*)(xl + o) = slo;
    }
    __syncthreads();
  }
}

// ---------------- prep: conv_w[co][ci][3][3] -> wT chunk-seg-major ----------
__global__ __launch_bounds__(256) void prep_w(const float* __restrict__ w,
                                              ushort* __restrict__ wh,
                                              ushort* __restrict__ wl) {
  int cc = blockIdx.x, sg = blockIdx.y, t = threadIdx.x;
  int e = t & 7, col = t >> 3;
  int ci = cc * 32 + sg * 8 + e;
  for (int chunk = 0; chunk < 8; ++chunk) {
    int co = blockIdx.z * 256 + chunk * 32 + col;
    const float* src = w + ((size_t)co * 1024 + ci) * 9;
    float v[9];
#pragma unroll
    for (int o = 0; o < 9; ++o) v[o] = src[o];
#pragma unroll
    for (int off = 0; off < 9; ++off) {
      ushort h2 = bf16rne(v[off]);
      float hf = __uint_as_float((uint)h2 << 16);
      ushort l2 = bf16rne(v[off] - hf);
      size_t oi = ((size_t)(off * 32 + cc) * 4 + sg) * 8192 + (size_t)co * 8 + e;
      wh[oi] = h2;
      wl[oi] = l2;
    }
  }
}

// ---------------- prep: head weights -> wH chunk-seg-major + bias[128] ------
__global__ __launch_bounds__(256) void prep_head(
    const float* __restrict__ score_w, const float* __restrict__ loc_w,
    const float* __restrict__ score_b, const float* __restrict__ loc_b,
    ushort* __restrict__ wh, ushort* __restrict__ wl, float* __restrict__ bh) {
  int idx = blockIdx.x * 256 + threadIdx.x;  // < 131072
  int o = idx >> 10, ci = idx & 1023;
  float v = 0.f;
  if (o < 15) v = score_w[o * 1024 + ci];
  else if (o < 75) v = loc_w[(o - 15) * 1024 + ci];
  ushort h2 = bf16rne(v);
  float hf = __uint_as_float((uint)h2 << 16);
  int cc = ci >> 5, sg = (ci >> 3) & 3, e = ci & 7;
  size_t oi = ((size_t)(cc * 4 + sg) * 128 + o) * 8 + e;
  wh[oi] = h2;
  wl[oi] = bf16rne(v - hf);
  if (idx < 128) bh[idx] = (idx < 15) ? score_b[idx] : ((idx < 75) ? loc_b[idx - 15] : 0.f);
}

// ---------------- conv GEMM (im2col): counted-vmcnt depth-2 pipeline --------
// M=4096, N=1024(BN=64/block), K=9216. A+B both LDS-staged (round-7 shape,
// 209us) -- round-8's B-in-regs exposed L2 latency (233us), reverted.
// THE fix targets the vmcnt(0)+s_barrier drain (~20-25% stall): 3 x 24KB LDS
// buffers, stages for kc+1,kc+2 in flight; each wave waits s_waitcnt vmcnt(6)
// (its OWN 6 loads for chunk kc done; kc+1's 6 still flying), THEN raw
// s_barrier => all waves' chunk-kc loads landed. Loads are never drained to 0
// in the loop (T4, m218). Buffer rotation mod 3: stage(kc+2) overwrites the
// buffer compute(kc-1) read -- ordered by this iteration's barrier (ds_reads
// are register-landed before their consuming MFMAs issue). sched_barrier(0)
// pins the asm waits. Numerics: same values, same K/MFMA order -> identical.
__global__ __launch_bounds__(256, 2) void gemm_conv(
    const ushort* __restrict__ Ahi, const ushort* __restrict__ Alo,
    const ushort* __restrict__ Bhi, const ushort* __restrict__ Blo,
    const float* __restrict__ bias, ushort* __restrict__ outHi,
    ushort* __restrict__ outLo) {
  constexpr int NC = 288;
  constexpr int ASEC = 128 * 32;             // ushorts per A section
  constexpr int BSEC = 64 * 32;              // ushorts per B section
  constexpr int BUFU = 2 * ASEC + 2 * BSEC;  // 12288 ushorts = 24 KB
  __shared__ ushort sm[3 * BUFU];            // 72 KB -> 2 blocks/CU
  const int t = threadIdx.x;
  const int m0 = blockIdx.x * 128;
  const int n0 = blockIdx.y * 64;

  const int lane = t & 63, wv = t >> 6;
  const int wm = (wv & 1) * 64, wn = (wv >> 1) * 32;
  const int rA = wm + (lane & 15);
  const int rB = wn + (lane & 15);
  const int segA = (lane >> 4) * 2048;  // A seg region base (bytes), BM*16
  const int segB = (lane >> 4) * 1024;  // B seg region base (bytes), BN*16

  // 6 gl_lds per thread per stage (4 A + 2 B) -- vmcnt accounting depends on it
  auto stage = [&](int c, ushort* buf) {
    ushort* secAh = buf;
    ushort* secAl = buf + ASEC;
    ushort* secBh = buf + 2 * ASEC;
    ushort* secBl = buf + 2 * ASEC + BSEC;
    int off = c >> 5, cc = c & 31;
    int oy = off / 3, ox = off - 3 * oy;
#pragma unroll
    for (int q = 0; q < 2; ++q) {
      int L = t + 256 * q;
      int row = L & 127, seg = L >> 7;
      int m = m0 + row, y = m >> 6, xq = m & 63;
      size_t aoff = ((size_t)(cc * 4 + seg) * 4356 + (y + oy) * 66 + (xq + ox)) * 16;
      gl_lds16((const char*)Ahi + aoff, (char*)secAh + L * 16);
      gl_lds16((const char*)Alo + aoff, (char*)secAl + L * 16);
    }
    {
      int L = t;
      int row = L & 63, seg = L >> 6;
      size_t boff = (((size_t)(off * 32 + cc) * 4 + seg) * 1024 + (n0 + row)) * 16;
      gl_lds16((const char*)Bhi + boff, (char*)secBh + L * 16);
      gl_lds16((const char*)Blo + boff, (char*)secBl + L * 16);
    }
  };

  floatx4 acc[4][2];
#pragma unroll
  for (int i = 0; i < 4; ++i)
#pragma unroll
    for (int j = 0; j < 2; ++j) acc[i][j] = (floatx4){0.f, 0.f, 0.f, 0.f};

  auto compute = [&](const ushort* sb) {
    const char* cAh = (const char*)sb;
    const char* cAl = (const char*)(sb + ASEC);
    const char* cBh = (const char*)(sb + 2 * ASEC);
    const char* cBl = (const char*)(sb + 2 * ASEC + BSEC);
    short8 ah[4], al[4], bh2[2], bl2[2];
#pragma unroll
    for (int i = 0; i < 4; ++i) {
      int pa = segA + (rA + 16 * i) * 16;
      ah[i] = *(const short8*)(cAh + pa);
      al[i] = *(const short8*)(cAl + pa);
    }
#pragma unroll
    for (int j = 0; j < 2; ++j) {
      int pb = segB + (rB + 16 * j) * 16;
      bh2[j] = *(const short8*)(cBh + pb);
      bl2[j] = *(const short8*)(cBl + pb);
    }
#pragma unroll
    for (int i = 0; i < 4; ++i)
#pragma unroll
      for (int j = 0; j < 2; ++j) {
        acc[i][j] = __builtin_amdgcn_mfma_f32_16x16x32_bf16(ah[i], bh2[j], acc[i][j], 0, 0, 0);
        acc[i][j] = __builtin_amdgcn_mfma_f32_16x16x32_bf16(ah[i], bl2[j], acc[i][j], 0, 0, 0);
        acc[i][j] = __builtin_amdgcn_mfma_f32_16x16x32_bf16(al[i], bh2[j], acc[i][j], 0, 0, 0);
      }
  };

  stage(0, sm);
  stage(1, sm + BUFU);
  int br = 0;   // read buffer index (chunk kc)
  int bw = 2;   // write buffer index (chunk kc+2)
  for (int kc = 0; kc < NC; ++kc) {
    __builtin_amdgcn_sched_barrier(0);
    if (kc < NC - 1) {
      asm volatile("s_waitcnt vmcnt(6)" ::: "memory");  // own chunk-kc loads done
    } else {
      asm volatile("s_waitcnt vmcnt(0)" ::: "memory");
    }
    __builtin_amdgcn_sched_barrier(0);
    __builtin_amdgcn_s_barrier();  // all waves' chunk-kc loads landed
    __builtin_amdgcn_sched_barrier(0);
    if (kc + 2 < NC) stage(kc + 2, sm + bw * BUFU);
    compute(sm + br * BUFU);
    br = (br == 2) ? 0 : br + 1;
    bw = (bw == 2) ? 0 : bw + 1;
  }

#pragma unroll
  for (int i = 0; i < 4; ++i)
#pragma unroll
    for (int j = 0; j < 2; ++j) {
      int nn = n0 + wn + 16 * j + (lane & 15);
      float bv = bias[nn];
#pragma unroll
      for (int r = 0; r < 4; ++r) {
        int mm = m0 + wm + 16 * i + (lane >> 4) * 4 + r;  // C: row=(lane>>4)*4+reg
        float v = fmaxf(acc[i][j][r] + bv, 0.f);
        ushort h2 = bf16rne(v);
        float hf = __uint_as_float((uint)h2 << 16);
        ushort l2 = bf16rne(v - hf);
        int cc = nn >> 5, sg = (nn >> 3) & 3, e = nn & 7;
        size_t ho = ((size_t)(cc * 4 + sg) * 4096 + mm) * 8 + e;
        outHi[ho] = h2;
        outLo[ho] = l2;
      }
    }
}

// ---------------- head GEMM: A-LDS + B-regs (round 8, kept: it helped) ------
template <int BM, int BN>
__global__ __launch_bounds__(256, 1) void gemm_head(
    const ushort* __restrict__ Ahi, const ushort* __restrict__ Alo,
    const ushort* __restrict__ Bhi, const ushort* __restrict__ Blo,
    const float* __restrict__ bias, int nChunks, float* __restrict__ outRaw) {
  constexpr int ASEC = BM * 32;
  constexpr int BUFU = 2 * ASEC;
  constexpr int WM = (BM >= 128) ? 2 : 1;
  constexpr int WN = 4 / WM;
  constexpr int MI = (BM / WM) / 16;
  constexpr int NJ = (BN / WN) / 16;
  __shared__ ushort sm[2 * BUFU];
  const int t = threadIdx.x;
  const int m0 = blockIdx.x * BM;
  const int n0 = blockIdx.y * BN;

  const int lane = t & 63, wv = t >> 6;
  const int wm = (wv % WM) * (BM / WM);
  const int wn = (wv / WM) * (BN / WN);
  const int rA = wm + (lane & 15);
  const int segA = (lane >> 4) * (BM * 16);

  auto stage = [&](int c, int bufIdx) {
    ushort* secAh = sm + bufIdx * BUFU;
    ushort* secAl = secAh + ASEC;
    for (int L = t; L < BM * 4; L += 256) {
      int row = L % BM, seg = L / BM;
      size_t aoff = ((size_t)(c * 4 + seg) * 4096 + (m0 + row)) * 16;
      gl_lds16((const char*)Ahi + aoff, (char*)secAh + L * 16);
      gl_lds16((const char*)Alo + aoff, (char*)secAl + L * 16);
    }
  };

  auto loadB = [&](int c, short8* bh, short8* bl) {
    int sg = lane >> 4;
#pragma unroll
    for (int j = 0; j < NJ; ++j) {
      int co = n0 + wn + (lane & 15) + 16 * j;
      size_t boff = (((size_t)(c * 4 + sg)) * 128 + co) * 16;
      bh[j] = *(const short8*)((const char*)Bhi + boff);
      bl[j] = *(const short8*)((const char*)Blo + boff);
    }
  };

  floatx4 acc[MI][NJ];
#pragma unroll
  for (int i = 0; i < MI; ++i)
#pragma unroll
    for (int j = 0; j < NJ; ++j) acc[i][j] = (floatx4){0.f, 0.f, 0.f, 0.f};

  auto compute = [&](const ushort* sb, const short8* bh2, const short8* bl2) {
    const char* cAh = (const char*)sb;
    const char* cAl = (const char*)(sb + ASEC);
    short8 ah[MI], al[MI];
#pragma unroll
    for (int i = 0; i < MI; ++i) {
      int pa = segA + (rA + 16 * i) * 16;
      ah[i] = *(const short8*)(cAh + pa);
      al[i] = *(const short8*)(cAl + pa);
    }
#pragma unroll
    for (int i = 0; i < MI; ++i)
#pragma unroll
      for (int j = 0; j < NJ; ++j) {
        acc[i][j] = __builtin_amdgcn_mfma_f32_16x16x32_bf16(ah[i], bh2[j], acc[i][j], 0, 0, 0);
        acc[i][j] = __builtin_amdgcn_mfma_f32_16x16x32_bf16(ah[i], bl2[j], acc[i][j], 0, 0, 0);
        acc[i][j] = __builtin_amdgcn_mfma_f32_16x16x32_bf16(al[i], bh2[j], acc[i][j], 0, 0, 0);
      }
  };

  short8 b0h[NJ], b0l[NJ], b1h[NJ], b1l[NJ];
  stage(0, 0);
  loadB(0, b0h, b0l);
  for (int kc = 0; kc < nChunks; kc += 2) {
    __syncthreads();
    if (kc + 1 < nChunks) { stage(kc + 1, 1); loadB(kc + 1, b1h, b1l); }
    compute(sm, b0h, b0l);
    __syncthreads();
    if (kc + 2 < nChunks) { stage(kc + 2, 0); loadB(kc + 2, b0h, b0l); }
    compute(sm + BUFU, b1h, b1l);
  }

#pragma unroll
  for (int i = 0; i < MI; ++i)
#pragma unroll
    for (int j = 0; j < NJ; ++j) {
      int nn = n0 + wn + 16 * j + (lane & 15);
      float bv = bias[nn];
#pragma unroll
      for (int r = 0; r < 4; ++r) {
        int mm = m0 + wm + 16 * i + (lane >> 4) * 4 + r;
        outRaw[(size_t)mm * 128 + nn] = acc[i][j][r] + bv;
      }
    }
}

// ---------------- decode + key + histogram ----------------------------------
__global__ __launch_bounds__(256) void decode_k(const float* __restrict__ raw,
                                                float* __restrict__ scores,
                                                float4* __restrict__ boxes,
                                                uint* __restrict__ key32,
                                                uint* __restrict__ hist) {
  int i = blockIdx.x * 256 + threadIdx.x;  // exactly 61440
  int m = i / 15, a = i - m * 15;
  int y = m >> 6, x = m & 63;
  const float* rp = raw + (size_t)m * 128;
  float logit = rp[a];
  float dx = rp[15 + 4 * a], dy = rp[16 + 4 * a];
  float dw = rp[17 + 4 * a], dh = rp[18 + 4 * a];
  int rr = a / 5, ss = a - rr * 5;
  float sc5 = (float)(2 << ss);
  float W = ((rr == 0) ? 23.f : (rr == 1) ? 16.f : 11.f) * sc5;
  float H = ((rr == 0) ? 12.f : (rr == 1) ? 16.f : 22.f) * sc5;
  float aw = W - 1.f, ah = H - 1.f;
  float ax = x * 16.f + 7.5f, ay = y * 16.f + 7.5f;
  float ox = dx * aw + ax, oyc = dy * ah + ay;
  float ow = expf(fminf(dw, 4.14f)) * aw * 0.5f;
  float oh = expf(fminf(dh, 4.14f)) * ah * 0.5f;
  float x1 = fminf(fmaxf(ox - ow, 0.f), 1023.f);
  float y1 = fminf(fmaxf(oyc - oh, 0.f), 1023.f);
  float x2 = fminf(fmaxf(ox + ow, 0.f), 1023.f);
  float y2 = fminf(fmaxf(oyc + oh, 0.f), 1023.f);
  bool inval = ((x2 - x1) < 16.f) || ((y2 - y1) < 16.f);
  float sc = inval ? -1.f : (1.f / (1.f + expf(-logit)));
  scores[i] = sc;
  boxes[i] = inval ? make_float4(-1.f, -1.f, -1.f, -1.f) : make_float4(x1, y1, x2, y2);
  uint kb = __float_as_uint(sc);
  uint key = (kb & 0x80000000u) ? ~kb : (kb | 0x80000000u);
  key32[i] = key;
  atomicAdd(&hist[key >> 16], 1u);
}

// ---------------- seg_sum: coalesced 256-entry segment sums of hist ---------
__global__ __launch_bounds__(256) void seg_sum(const uint* __restrict__ hist,
                                               uint* __restrict__ segsum) {
  __shared__ uint red[256];
  int b = blockIdx.x, t = threadIdx.x;
  red[t] = hist[b * 256 + t];
  __syncthreads();
  for (int d = 128; d > 0; d >>= 1) {
    if (t < d) red[t] += red[t + d];
    __syncthreads();
  }
  if (t == 0) segsum[b] = red[0];
}

// ---------------- find 16-bit prefix threshold for top-6000 -----------------
__global__ __launch_bounds__(256) void find_t16(const uint* __restrict__ hist,
                                                const uint* __restrict__ segsum,
                                                uint* __restrict__ selT) {
  __shared__ uint ps[256];
  __shared__ int segS;
  int t = threadIdx.x;
  ps[t] = segsum[t];
  __syncthreads();
  for (int d = 1; d < 256; d <<= 1) {
    uint v = ps[t] + ((t + d < 256) ? ps[t + d] : 0u);
    __syncthreads();
    ps[t] = v;
    __syncthreads();
  }
  if (ps[t] >= 6000u && (t == 255 || ps[t + 1] < 6000u)) segS = t;
  __syncthreads();
  int sg = segS;
  uint base = (sg == 255) ? 0u : ps[sg + 1];
  uint h2 = hist[sg * 256 + t];
  __syncthreads();
  ps[t] = h2;
  __syncthreads();
  for (int d = 1; d < 256; d <<= 1) {
    uint v = ps[t] + ((t + d < 256) ? ps[t + d] : 0u);
    __syncthreads();
    ps[t] = v;
    __syncthreads();
  }
  if (base + ps[t] >= 6000u && (t == 255 || base + ps[t + 1] < 6000u))
    *selT = (uint)(sg * 256 + t);
}

// ---------------- gather candidates (prefix >= T16) -------------------------
__global__ __launch_bounds__(256) void gather_k(const uint* __restrict__ key32,
                                                const uint* __restrict__ selT,
                                                uint* __restrict__ cnt,
                                                u64* __restrict__ cand) {
  int i = blockIdx.x * 256 + threadIdx.x;  // exactly 61440
  uint T = *selT;
  uint k = key32[i];
  if ((k >> 16) >= T) {
    uint pos = atomicAdd(cnt, 1u);
    if (pos < 8192) cand[pos] = ((u64)k << 32) | (u64)(~(uint)i);
  }
}

// ---------------- single-block bitonic sort (desc) + gather top-6000 --------
__global__ __launch_bounds__(1024) void sort_gather(
    const u64* __restrict__ cand, const uint* __restrict__ cnt,
    const float* __restrict__ scores, const float4* __restrict__ boxes,
    float* __restrict__ sortedS, float4* __restrict__ sortedB) {
  extern __shared__ u64 sk[];  // 8192 * 8 = 64 KB
  int t = threadIdx.x;
  int C = (int)*cnt;
  if (C > 8192) C = 8192;
  for (int j = t; j < 8192; j += 1024) sk[j] = (j < C) ? cand[j] : 0ull;
  __syncthreads();
  for (int k = 2; k <= 8192; k <<= 1) {
    for (int j2 = k >> 1; j2 > 0; j2 >>= 1) {
      for (int p = t; p < 4096; p += 1024) {
        int i = ((p & ~(j2 - 1)) << 1) | (p & (j2 - 1));
        int ix = i | j2;
        u64 a = sk[i], b = sk[ix];
        bool ddir = (i & k) != 0;
        if ((a < b) != ddir) { sk[i] = b; sk[ix] = a; }
      }
      __syncthreads();
    }
  }
  for (int j = t; j < 6016; j += 1024) {
    if (j < 6000) {
      u64 key = sk[j];
      uint idx = ~(uint)(key & 0xffffffffu);
      sortedS[j] = scores[idx];
      sortedB[j] = boxes[idx];
    } else {
      sortedS[j] = -1.f;
      sortedB[j] = make_float4(0.f, 0.f, 0.f, 0.f);
    }
  }
}

// ---------------- IoU suppression bitmask: mask[row][128 u64 words] ---------
__global__ __launch_bounds__(64) void iou_mask(const float4* __restrict__ boxes,
                                               u64* __restrict__ mask) {
  __shared__ float cx1[64], cy1[64], cx2[64], cy2[64], car[64];
  int bi = blockIdx.x, bj = blockIdx.y, t = threadIdx.x;
  float4 cb = boxes[bj * 64 + t];
  cx1[t] = cb.x; cy1[t] = cb.y; cx2[t] = cb.z; cy2[t] = cb.w;
  car[t] = (cb.z - cb.x) * (cb.w - cb.y);
  __syncthreads();
  int r = bi * 64 + t;
  float4 rb = boxes[r];
  float ra = (rb.z - rb.x) * (rb.w - rb.y);
  u64 wd = 0;
#pragma unroll 8
  for (int j = 0; j < 64; ++j) {
    float iw = fmaxf(fminf(rb.z, cx2[j]) - fmaxf(rb.x, cx1[j]), 0.f);
    float ih = fmaxf(fminf(rb.w, cy2[j]) - fmaxf(rb.y, cy1[j]), 0.f);
    float inter = iw * ih;
    float iou = inter / (ra + car[j] - inter + 1e-12f);
    if (iou > 0.7f && r != bj * 64 + j) wd |= (1ull << j);
  }
  mask[(size_t)r * 128 + bj] = wd;
}

// ---------------- serial NMS scan (1 wave), 2-slot pipelined row loads ------
__global__ __launch_bounds__(64) void nms_scan(const u64* __restrict__ mask,
                                               const float* __restrict__ sortedS,
                                               const float4* __restrict__ sortedB,
                                               float* __restrict__ out) {
  __shared__ int klist[300];
  int lane = threadIdx.x;
  u64 Sx = 0, Sy = 0;  // lane l owns suppression words 2l and 2l+1
  for (int w2 = 0; w2 < 94; ++w2) {
    bool neg = sortedS[w2 * 64 + lane] < 0.f;
    u64 m2 = __ballot(neg);
    if ((w2 >> 1) == lane) { if (w2 & 1) Sy = m2; else Sx = m2; }
  }
  int count = 0;
  for (int w2 = 0; w2 < 94; ++w2) {
    u64 cur = __shfl((w2 & 1) ? Sy : Sx, w2 >> 1);
    u64 rem = ~cur;
    if (w2 == 93) rem &= (1ull << 48) - 1;  // rows 6000..6015 are pad
    if (!rem) continue;
    int bA = __builtin_ctzll(rem);
    ulonglong2 vA = ((const ulonglong2*)(mask + (size_t)(w2 * 64 + bA) * 128))[lane];
    int bB;
    ulonglong2 vB;
    for (;;) {
      {  // --- slot A current, speculate into slot B ---
        u64 remS = (bA == 63) ? 0ull : (rem & (~0ull << (bA + 1)));
        bB = remS ? __builtin_ctzll(remS) : -1;
        if (bB >= 0)
          vB = ((const ulonglong2*)(mask + (size_t)(w2 * 64 + bB) * 128))[lane];
        if (lane == 0) klist[count] = w2 * 64 + bA;
        count++;
        if (count == 300) goto done;
        Sx |= vA.x;
        Sy |= vA.y;
        u64 cur2 = __shfl((w2 & 1) ? Sy : Sx, w2 >> 1);
        rem = remS & ~cur2;
        if (!rem) break;
        int bn = __builtin_ctzll(rem);
        if (bn != bB) {  // misspeculation: reissue
          bB = bn;
          vB = ((const ulonglong2*)(mask + (size_t)(w2 * 64 + bB) * 128))[lane];
        }
      }
      {  // --- slot B current, speculate into slot A ---
        u64 remS = (bB == 63) ? 0ull : (rem & (~0ull << (bB + 1)));
        bA = remS ? __builtin_ctzll(remS) : -1;
        if (bA >= 0)
          vA = ((const ulonglong2*)(mask + (size_t)(w2 * 64 + bA) * 128))[lane];
        if (lane == 0) klist[count] = w2 * 64 + bB;
        count++;
        if (count == 300) goto done;
        Sx |= vB.x;
        Sy |= vB.y;
        u64 cur2 = __shfl((w2 & 1) ? Sy : Sx, w2 >> 1);
        rem = remS & ~cur2;
        if (!rem) break;
        int bn = __builtin_ctzll(rem);
        if (bn != bA) {  // misspeculation: reissue
          bA = bn;
          vA = ((const ulonglong2*)(mask + (size_t)(w2 * 64 + bA) * 128))[lane];
        }
      }
    }
  }
done:
  __syncthreads();
  for (int j = lane; j < 300; j += 64) {
    float s;
    float4 bb;
    if (j < count) {
      int i = klist[j];
      s = sortedS[i];
      bb = sortedB[i];
    } else {
      s = -1.f;
      bb = make_float4(-1.f, -1.f, -1.f, -1.f);
    }
    out[j * 5 + 0] = s;
    out[j * 5 + 1] = bb.x;
    out[j * 5 + 2] = bb.y;
    out[j * 5 + 3] = bb.z;
    out[j * 5 + 4] = bb.w;
  }
}

// ---------------- workspace layout (bytes) ----------------------------------
constexpr size_t O_XH = 0;                // 8,921,088   xpadT hi
constexpr size_t O_XL = 8921088;          // 8,921,088   xpadT lo
constexpr size_t O_WTH = 17842176;        // 18,874,368  wT hi
constexpr size_t O_WTL = 36716544;        // 18,874,368  wT lo
constexpr size_t O_HH = 55590912;         // 8,388,608   h hi
constexpr size_t O_HL = 63979520;         // 8,388,608   h lo
constexpr size_t O_WHH = 72368128;        // 262,144     head w hi
constexpr size_t O_WHL = 72630272;        // 262,144     head w lo
constexpr size_t O_BHD = 72892416;        // 512         head bias
constexpr size_t O_SC = 72892928;         // 245,760     scores
constexpr size_t O_BX = 73138688;         // 983,040     boxes (float4)
constexpr size_t O_KEY = 74121728;        // 245,760     key32
constexpr size_t O_HIST = 74367488;       // 262,144     histogram
constexpr size_t O_CNT = 74629632;        // 256         atomic counter
constexpr size_t O_CAND = 74629888;       // 65,536      candidates
constexpr size_t O_SELT = 74695424;       // 256         T16
constexpr size_t O_SS = 74695680;         // 24,064      sorted scores [6016]
constexpr size_t O_SB = 74719744;         // 96,256      sorted boxes  [6016]
// aliases (regions dead by the time these are written):
constexpr size_t O_RAW = 0;               // 2,097,152  raw head out (aliases xpadT, dead after conv GEMM)
constexpr size_t O_MASK = 17842176;       // 6,160,384  NMS mask (aliases wT, dead after conv GEMM)
constexpr size_t O_SEG = 24002560;        // 1,024      segsum (aliases wT tail)
// total distinct footprint ~74.8 MB

extern "C" void kernel_launch(void* const* d_in, const int* in_sizes, int n_in,
                              void* d_out, int out_size, void* d_ws,
                              size_t ws_size, hipStream_t stream) {
  (void)in_sizes; (void)n_in; (void)out_size; (void)ws_size;
  const float* x = (const float*)d_in[1];
  const float* conv_w = (const float*)d_in[2];
  const float* conv_b = (const float*)d_in[3];
  const float* score_w = (const float*)d_in[4];
  const float* score_b = (const float*)d_in[5];
  const float* loc_w = (const float*)d_in[6];
  const float* loc_b = (const float*)d_in[7];
  float* out = (float*)d_out;
  char* ws = (char*)d_ws;

  ushort* xh = (ushort*)(ws + O_XH);
  ushort* xl = (ushort*)(ws + O_XL);
  ushort* wTh = (ushort*)(ws + O_WTH);
  ushort* wTl = (ushort*)(ws + O_WTL);
  ushort* hh = (ushort*)(ws + O_HH);
  ushort* hl = (ushort*)(ws + O_HL);
  ushort* wHh = (ushort*)(ws + O_WHH);
  ushort* wHl = (ushort*)(ws + O_WHL);
  float* biasH = (float*)(ws + O_BHD);
  float* raw = (float*)(ws + O_RAW);
  float* scores = (float*)(ws + O_SC);
  float4* boxes = (float4*)(ws + O_BX);
  uint* key32 = (uint*)(ws + O_KEY);
  uint* hist = (uint*)(ws + O_HIST);
  uint* cnt = (uint*)(ws + O_CNT);
  u64* cand = (u64*)(ws + O_CAND);
  uint* selT = (uint*)(ws + O_SELT);
  float* sortedS = (float*)(ws + O_SS);
  float4* sortedB = (float4*)(ws + O_SB);
  u64* mask = (u64*)(ws + O_MASK);
  uint* segsum = (uint*)(ws + O_SEG);

  // zero the padded-input borders (whole buffer) and histogram+counter
  hipMemsetAsync(ws + O_XH, 0, 2 * 8921088, stream);
  hipMemsetAsync(ws + O_HIST, 0, 262144 + 256, stream);

  prep_x<<<dim3(32, 4, 2), 256, 0, stream>>>(x, xh, xl);
  prep_w<<<dim3(32, 4, 4), 256, 0, stream>>>(conv_w, wTh, wTl);
  prep_head<<<512, 256, 0, stream>>>(score_w, loc_w, score_b, loc_b, wHh, wHl, biasH);

  // conv: M=4096, N=1024, K=9216 -> h (relu, bf16 hi/lo); tile 128x64,
  // grid (32,16)=512 blocks -> 2 blocks/CU; counted-vmcnt depth-2 pipeline
  gemm_conv<<<dim3(32, 16), 256, 0, stream>>>(xh, xl, wTh, wTl, conv_b, hh, hl);
  // heads: M=4096, N=128(pad), K=1024 -> raw f32; tile 32x128, 128 blocks
  gemm_head<32, 128><<<dim3(128, 1), 256, 0, stream>>>(hh, hl, wHh, wHl, biasH,
                                                       32, raw);

  decode_k<<<240, 256, 0, stream>>>(raw, scores, boxes, key32, hist);
  seg_sum<<<256, 256, 0, stream>>>(hist, segsum);
  find_t16<<<1, 256, 0, stream>>>(hist, segsum, selT);
  gather_k<<<240, 256, 0, stream>>>(key32, selT, cnt, cand);
  sort_gather<<<1, 1024, 65536, stream>>>(cand, cnt, scores, boxes, sortedS, sortedB);
  iou_mask<<<dim3(94, 94), 64, 0, stream>>>(sortedB, mask);
  nms_scan<<<1, 64, 0, stream>>>(mask, sortedS, sortedB, out);
}